// Round 3
// baseline (591.551 us; speedup 1.0000x reference)
//
#include <hip/hip_runtime.h>
#include <hip/hip_bf16.h>
#include <stdint.h>

typedef __attribute__((ext_vector_type(8))) short short8;
typedef __attribute__((ext_vector_type(4))) float f32x4;
typedef __attribute__((ext_vector_type(4))) unsigned short ushort4v;

#define MFMA_BF16(a,b,c) __builtin_amdgcn_mfma_f32_16x16x32_bf16((a),(b),(c),0,0,0)

static __device__ __forceinline__ unsigned short f2bf(float f){
  union { float fv; unsigned int u; } c; c.fv = f;
  unsigned int u = c.u;
  return (unsigned short)((u + 0x7fffu + ((u >> 16) & 1u)) >> 16);
}

static __device__ __forceinline__ unsigned int cvtpk(float a, float b){
  unsigned int r;
  asm("v_cvt_pk_bf16_f32 %0, %1, %2" : "=v"(r) : "v"(a), "v"(b));
  return r;
}

static __device__ __forceinline__ void gload_lds16(const void* g, void* l){
  __builtin_amdgcn_global_load_lds(
      (const __attribute__((address_space(1))) void*)g,
      (__attribute__((address_space(3))) void*)l, 16, 0, 0);
}

static __device__ __forceinline__ float wred_sum(float v){
  #pragma unroll
  for (int m = 32; m; m >>= 1) v += __shfl_xor(v, m, 64);
  return v;
}

static __device__ __forceinline__ void unpack8(uint4 u, float* f){
  f[0] = __uint_as_float(u.x << 16); f[1] = __uint_as_float(u.x & 0xFFFF0000u);
  f[2] = __uint_as_float(u.y << 16); f[3] = __uint_as_float(u.y & 0xFFFF0000u);
  f[4] = __uint_as_float(u.z << 16); f[5] = __uint_as_float(u.z & 0xFFFF0000u);
  f[6] = __uint_as_float(u.w << 16); f[7] = __uint_as_float(u.w & 0xFFFF0000u);
}

// ---------------- conversion kernels ----------------
__global__ __launch_bounds__(256) void cvt_x_kernel(const float* __restrict__ x,
                                                    unsigned short* __restrict__ o){
  int i = blockIdx.x * 256 + threadIdx.x;
  float4 f = ((const float4*)x)[i];
  ushort4v r;
  r[0] = f2bf(f.x); r[1] = f2bf(f.y); r[2] = f2bf(f.z); r[3] = f2bf(f.w);
  ((ushort4v*)o)[i] = r;
}

__global__ __launch_bounds__(256) void cvt_w_kernel(const float* __restrict__ Wq,
                                                    const float* __restrict__ Wk,
                                                    const float* __restrict__ Wv,
                                                    const float* __restrict__ Ws,
                                                    unsigned short* __restrict__ B){
  int i = blockIdx.x * 256 + threadIdx.x;
  int which = i >> 18;
  const float* src = (which == 0) ? Wq : (which == 1) ? Wk : (which == 2) ? Wv : Ws;
  float4 f = ((const float4*)src)[i & 262143];
  ushort4v r;
  r[0] = f2bf(f.x); r[1] = f2bf(f.y); r[2] = f2bf(f.z); r[3] = f2bf(f.w);
  ((ushort4v*)B)[i] = r;
}

__global__ void wb_prep_kernel(const float* __restrict__ Wb,
                               float* __restrict__ wba, float* __restrict__ wbb){
  int e = blockIdx.x * 256 + threadIdx.x;
  if (e < 1024){
    wba[e] = Wb[e]        + Wb[2048 + e];
    wbb[e] = Wb[1024 + e] - Wb[2048 + e];
  }
}

// masks -> bf16 {0,1} planes (written into dead xbf/bm workspace, after gemm)
__global__ __launch_bounds__(256) void mask_prep_kernel(const int* __restrict__ m,
                                                        const int* __restrict__ wm,
                                                        unsigned short* __restrict__ mb,
                                                        unsigned short* __restrict__ wb){
  int i = blockIdx.x * 256 + threadIdx.x;          // 524288 threads, 8 elems each
  const int4* mp = (const int4*)(m + (size_t)i * 8);
  const int4* wp = (const int4*)(wm + (size_t)i * 8);
  int4 a0 = mp[0], a1 = mp[1], b0 = wp[0], b1 = wp[1];
  short8 rm, rw;
  rm[0] = a0.x ? 0x3F80 : 0; rm[1] = a0.y ? 0x3F80 : 0;
  rm[2] = a0.z ? 0x3F80 : 0; rm[3] = a0.w ? 0x3F80 : 0;
  rm[4] = a1.x ? 0x3F80 : 0; rm[5] = a1.y ? 0x3F80 : 0;
  rm[6] = a1.z ? 0x3F80 : 0; rm[7] = a1.w ? 0x3F80 : 0;
  rw[0] = b0.x ? 0x3F80 : 0; rw[1] = b0.y ? 0x3F80 : 0;
  rw[2] = b0.z ? 0x3F80 : 0; rw[3] = b0.w ? 0x3F80 : 0;
  rw[4] = b1.x ? 0x3F80 : 0; rw[5] = b1.y ? 0x3F80 : 0;
  rw[6] = b1.z ? 0x3F80 : 0; rw[7] = b1.w ? 0x3F80 : 0;
  ((short8*)mb)[i] = rm;
  ((short8*)wb)[i] = rw;
}

// ---------------- fused projection GEMM ----------------
__global__ __launch_bounds__(256, 2) void gemm_proj_kernel(
    const unsigned short* __restrict__ X, const unsigned short* __restrict__ B,
    unsigned short* __restrict__ qb, unsigned short* __restrict__ kb,
    unsigned short* __restrict__ vT, float* __restrict__ rb)
{
  __shared__ unsigned short As[128 * 32];
  __shared__ unsigned short Bs[128 * 32];
  const int tid = threadIdx.x;
  const int w = tid >> 6, l = tid & 63;
  const int lr = l & 15, lq = l >> 4;
  const int wr = w >> 1, wc = w & 1;
  const int bid = ((blockIdx.x & 7) << 8) | (blockIdx.x >> 3);   // XCD swizzle (2048 = 8*256)
  const int m0 = (bid >> 5) * 128;
  const int n0 = (bid & 31) * 128;
  f32x4 acc[4][4] = {};

  for (int k0 = 0; k0 < 1024; k0 += 32){
    #pragma unroll
    for (int i = 0; i < 2; i++){
      int c = i * 256 + tid;
      gload_lds16(X + (size_t)(m0 + (c >> 2)) * 1024 + k0 + (c & 3) * 8,
                  As + (i * 256 + w * 64) * 8);
      gload_lds16(B + (size_t)(n0 + (c >> 2)) * 1024 + k0 + (c & 3) * 8,
                  Bs + (i * 256 + w * 64) * 8);
    }
    __syncthreads();
    short8 av[4], bv[4];
    #pragma unroll
    for (int mf = 0; mf < 4; mf++)
      av[mf] = *(const short8*)(As + (wr * 64 + mf * 16 + lr) * 32 + lq * 8);
    #pragma unroll
    for (int nf = 0; nf < 4; nf++)
      bv[nf] = *(const short8*)(Bs + (wc * 64 + nf * 16 + lr) * 32 + lq * 8);
    #pragma unroll
    for (int mf = 0; mf < 4; mf++)
      #pragma unroll
      for (int nf = 0; nf < 4; nf++)
        acc[mf][nf] = MFMA_BF16(av[mf], bv[nf], acc[mf][nf]);
    __syncthreads();
  }

  const int which = (n0 >> 10);
  #pragma unroll
  for (int mf = 0; mf < 4; mf++){
    #pragma unroll
    for (int nf = 0; nf < 4; nf++){
      const int col = n0 + wc * 64 + nf * 16 + lr;
      const int o = col & 1023;
      #pragma unroll
      for (int rg = 0; rg < 4; rg++){
        const int rowi = m0 + wr * 64 + mf * 16 + lq * 4 + rg;
        const float val = acc[mf][nf][rg];
        if (which == 3){
          rb[(size_t)rowi * 1024 + o] = val;
        } else {
          const int s = rowi >> 4, bb = rowi & 15;
          const int bh = bb * 16 + (o >> 6), d = o & 63;
          if (which == 0)      qb[((size_t)bh * 512 + s) * 64 + d] = f2bf(val);
          else if (which == 1) kb[((size_t)bh * 512 + s) * 64 + d] = f2bf(val);
          else                 vT[((size_t)bh * 64 + d) * 512 + s] = f2bf(val);
        }
      }
    }
  }
}

// ---------------- fused attention ----------------
// 32 q-rows/block, 8 waves; wave w owns k-slice [64w, 64w+64).
// Phase A: e1 = exp(s/8) stored bf16 in LDS (no max-subtract; |s| small).
// Phase B: z1 = sum(e1*m); e2 = exp2(e1*m*(log2e/z1))*wm; store e2 bf16; fin = 1/(z2+1e-10).
// Phase C: PV via MFMA, ds_add_f32 partial combine, out *= fin per row.
__global__ __launch_bounds__(512, 4) void attn_kernel(
    const unsigned short* __restrict__ qg, const unsigned short* __restrict__ kg,
    const unsigned short* __restrict__ vt,
    const unsigned short* __restrict__ mbf, const unsigned short* __restrict__ wbf,
    float* __restrict__ outp)
{
  __shared__ __align__(16) unsigned short sE[32 * 520];   // e1 -> attn weights (in-place)
  __shared__ float part[2 * 16 * 68];
  __shared__ float sfin[32];
  const int bid = ((blockIdx.x & 7) << 9) | (blockIdx.x >> 3);  // XCD swizzle (4096 = 8*512)
  const int qt = bid & 15, h = (bid >> 4) & 15, b = bid >> 8;
  const int bh = b * 16 + h;
  const int tid = threadIdx.x, w = tid >> 6, l = tid & 63;
  const int lr = l & 15, lq = l >> 4;
  const unsigned short* qp = qg + ((size_t)bh * 512 + qt * 32) * 64;
  const unsigned short* kp = kg + (size_t)bh * 512 * 64;
  const unsigned short* vp = vt + (size_t)bh * 64 * 512;
  const int kbase = w * 64;

  for (int i = tid; i < 2176; i += 512) part[i] = 0.f;

  // ---- Phase A: QK^T for 2 q-tiles x 4 k-frags, then exp -> bf16 LDS ----
  short8 qa[2][2];
  #pragma unroll
  for (int t = 0; t < 2; t++){
    qa[t][0] = *(const short8*)(qp + (t * 16 + lr) * 64 + lq * 8);
    qa[t][1] = *(const short8*)(qp + (t * 16 + lr) * 64 + 32 + lq * 8);
  }
  f32x4 acc[2][4] = {};
  #pragma unroll
  for (int kf = 0; kf < 4; kf++){
    const unsigned short* kr = kp + (size_t)(kbase + kf * 16 + lr) * 64;
    short8 k0 = *(const short8*)(kr + lq * 8);
    short8 k1 = *(const short8*)(kr + 32 + lq * 8);
    #pragma unroll
    for (int t = 0; t < 2; t++){
      acc[t][kf] = MFMA_BF16(qa[t][0], k0, acc[t][kf]);
      acc[t][kf] = MFMA_BF16(qa[t][1], k1, acc[t][kf]);
    }
  }
  const float CEXP = 0.18033688011112042f;   // 0.125 * log2(e)
  #pragma unroll
  for (int t = 0; t < 2; t++){
    #pragma unroll
    for (int kf = 0; kf < 4; kf++){
      float a0 = __builtin_amdgcn_exp2f(acc[t][kf][0] * CEXP);
      float a1 = __builtin_amdgcn_exp2f(acc[t][kf][1] * CEXP);
      float a2 = __builtin_amdgcn_exp2f(acc[t][kf][2] * CEXP);
      float a3 = __builtin_amdgcn_exp2f(acc[t][kf][3] * CEXP);
      unsigned int p01 = cvtpk(a0, a1), p23 = cvtpk(a2, a3);
      const int row = t * 16 + lq * 4;
      const int col = kbase + kf * 16 + lr;
      sE[(row    ) * 520 + col] = (unsigned short)(p01 & 0xFFFFu);
      sE[(row + 1) * 520 + col] = (unsigned short)(p01 >> 16);
      sE[(row + 2) * 520 + col] = (unsigned short)(p23 & 0xFFFFu);
      sE[(row + 3) * 520 + col] = (unsigned short)(p23 >> 16);
    }
  }
  __syncthreads();

  // ---- Phase B: double masked softmax, wave w owns rows 4w..4w+3 ----
  #pragma unroll 2
  for (int rr = 0; rr < 4; rr++){
    const int row = w * 4 + rr;
    const int qrow = qt * 32 + row;
    uint4 mu = *(const uint4*)(mbf + ((size_t)b * 512 + qrow) * 512 + l * 8);
    uint4 wu = *(const uint4*)(wbf + ((size_t)b * 512 + qrow) * 512 + l * 8);
    uint4 ev = *(const uint4*)(sE + row * 520 + l * 8);
    float e1[8], mf[8], wf[8];
    unpack8(ev, e1); unpack8(mu, mf); unpack8(wu, wf);
    float em[8]; float z = 0.f;
    #pragma unroll
    for (int j = 0; j < 8; j++){ em[j] = e1[j] * mf[j]; z += em[j]; }
    z = wred_sum(z);
    const float i1L = 1.4426950408889634f / z;
    float e2[8]; float z2 = 0.f;
    #pragma unroll
    for (int j = 0; j < 8; j++){
      e2[j] = __builtin_amdgcn_exp2f(em[j] * i1L) * wf[j];
      z2 += e2[j];
    }
    z2 = wred_sum(z2);
    uint4 o;
    o.x = cvtpk(e2[0], e2[1]); o.y = cvtpk(e2[2], e2[3]);
    o.z = cvtpk(e2[4], e2[5]); o.w = cvtpk(e2[6], e2[7]);
    *(uint4*)(sE + row * 520 + l * 8) = o;
    if (l == 0) sfin[row] = 1.f / (z2 + 1e-10f);
  }
  __syncthreads();

  // ---- Phase C: out = A @ V over this wave's k-slice, ds_add combine ----
  f32x4 ao[2][4] = {};
  #pragma unroll
  for (int ks = 0; ks < 2; ks++){
    short8 af0 = *(const short8*)(sE + (     lr) * 520 + kbase + ks * 32 + lq * 8);
    short8 af1 = *(const short8*)(sE + (16 + lr) * 520 + kbase + ks * 32 + lq * 8);
    #pragma unroll
    for (int nf = 0; nf < 4; nf++){
      short8 vf = *(const short8*)(vp + (size_t)(nf * 16 + lr) * 512 + kbase + ks * 32 + lq * 8);
      ao[0][nf] = MFMA_BF16(af0, vf, ao[0][nf]);
      ao[1][nf] = MFMA_BF16(af1, vf, ao[1][nf]);
    }
  }
  #pragma unroll
  for (int t = 0; t < 2; t++)
    #pragma unroll
    for (int nf = 0; nf < 4; nf++)
      #pragma unroll
      for (int rg = 0; rg < 4; rg++)
        atomicAdd(&part[(t * 16 + lq * 4 + rg) * 68 + nf * 16 + lr], ao[t][nf][rg]);
  __syncthreads();

  // ---- output: 2048 f32, scale by per-row fin ----
  {
    const int idx = tid * 4;
    const int row = idx >> 6, d = idx & 63;
    const float fin = sfin[row];
    float4 o;
    o.x = part[row * 68 + d    ] * fin;
    o.y = part[row * 68 + d + 1] * fin;
    o.z = part[row * 68 + d + 2] * fin;
    o.w = part[row * 68 + d + 3] * fin;
    *(float4*)(outp + ((size_t)(qt * 32 + row) * 16 + b) * 1024 + h * 64 + d) = o;
  }
}

// ---------------- gate + mix ----------------
__global__ __launch_bounds__(256) void gate_kernel(
    const float* __restrict__ outp, const float* __restrict__ rb,
    const float* __restrict__ wba, const float* __restrict__ wbb,
    float* __restrict__ y)
{
  const int t = blockIdx.x * 4 + (threadIdx.x >> 6);
  const int l = threadIdx.x & 63;
  const float* o = outp + (size_t)t * 1024;
  const float* r = rb + (size_t)t * 1024;
  float ov[16], rv[16];
  float acc = 0.f;
  #pragma unroll
  for (int j = 0; j < 16; j++){
    const int e = j * 64 + l;
    ov[j] = o[e]; rv[j] = r[e];
    acc += ov[j] * wba[e] + rv[j] * wbb[e];
  }
  const float dot = wred_sum(acc);
  const float g = 1.f / (1.f + __builtin_amdgcn_exp2f(-dot * 1.4426950408889634f));
  float* yo = y + (size_t)t * 1024;
  #pragma unroll
  for (int j = 0; j < 16; j++){
    const int e = j * 64 + l;
    yo[e] = g * rv[j] + (1.f - g) * ov[j];
  }
}

// ---------------- launch ----------------
extern "C" void kernel_launch(void* const* d_in, const int* in_sizes, int n_in,
                              void* d_out, int out_size, void* d_ws, size_t ws_size,
                              hipStream_t stream)
{
  (void)in_sizes; (void)n_in; (void)out_size; (void)ws_size;
  const float* x   = (const float*)d_in[0];
  const int* mask  = (const int*)d_in[1];
  const int* wmask = (const int*)d_in[2];
  const float* Wq  = (const float*)d_in[3];
  const float* Wk  = (const float*)d_in[4];
  const float* Wv  = (const float*)d_in[5];
  const float* Ws  = (const float*)d_in[6];
  const float* Wb  = (const float*)d_in[7];

  char* ws = (char*)d_ws;
  unsigned short* xbf = (unsigned short*)ws; ws += 16777216;
  unsigned short* bm  = (unsigned short*)ws; ws += 8388608;
  unsigned short* qb  = (unsigned short*)ws; ws += 16777216;
  unsigned short* kb  = (unsigned short*)ws; ws += 16777216;
  unsigned short* vT  = (unsigned short*)ws; ws += 16777216;
  float* rb  = (float*)ws; ws += 33554432;
  float* op  = (float*)ws; ws += 33554432;
  float* wba = (float*)ws; ws += 4096;
  float* wbb = (float*)ws; ws += 4096;
  // mask bf16 planes reuse xbf (8.39MB of 16MB) and bm (8.39MB) after gemm
  unsigned short* mbf = xbf;
  unsigned short* wbf = bm;

  cvt_x_kernel<<<8192, 256, 0, stream>>>(x, xbf);
  cvt_w_kernel<<<4096, 256, 0, stream>>>(Wq, Wk, Wv, Ws, bm);
  wb_prep_kernel<<<4, 256, 0, stream>>>(Wb, wba, wbb);
  gemm_proj_kernel<<<2048, 256, 0, stream>>>(xbf, bm, qb, kb, vT, rb);
  mask_prep_kernel<<<2048, 256, 0, stream>>>(mask, wmask, mbf, wbf);
  attn_kernel<<<4096, 512, 0, stream>>>(qb, kb, vT, mbf, wbf, op);
  gate_kernel<<<2048, 256, 0, stream>>>(op, rb, wba, wbb, (float*)d_out);
}

// Round 4
// 317.419 us; speedup vs baseline: 1.8636x; 1.8636x over previous
//
#include <hip/hip_runtime.h>
#include <hip/hip_bf16.h>
#include <stdint.h>

typedef __attribute__((ext_vector_type(8))) short short8;
typedef __attribute__((ext_vector_type(4))) float f32x4;
typedef __attribute__((ext_vector_type(4))) unsigned short ushort4v;

#define MFMA_BF16(a,b,c) __builtin_amdgcn_mfma_f32_16x16x32_bf16((a),(b),(c),0,0,0)

static __device__ __forceinline__ unsigned short f2bf(float f){
  union { float fv; unsigned int u; } c; c.fv = f;
  unsigned int u = c.u;
  return (unsigned short)((u + 0x7fffu + ((u >> 16) & 1u)) >> 16);
}

static __device__ __forceinline__ unsigned int cvtpk(float a, float b){
  unsigned int r;
  asm("v_cvt_pk_bf16_f32 %0, %1, %2" : "=v"(r) : "v"(a), "v"(b));
  return r;
}

static __device__ __forceinline__ void gload_lds16(const void* g, void* l){
  __builtin_amdgcn_global_load_lds(
      (const __attribute__((address_space(1))) void*)g,
      (__attribute__((address_space(3))) void*)l, 16, 0, 0);
}

static __device__ __forceinline__ float wred_sum(float v){
  #pragma unroll
  for (int m = 32; m; m >>= 1) v += __shfl_xor(v, m, 64);
  return v;
}

static __device__ __forceinline__ void unpack8(uint4 u, float* f){
  f[0] = __uint_as_float(u.x << 16); f[1] = __uint_as_float(u.x & 0xFFFF0000u);
  f[2] = __uint_as_float(u.y << 16); f[3] = __uint_as_float(u.y & 0xFFFF0000u);
  f[4] = __uint_as_float(u.z << 16); f[5] = __uint_as_float(u.z & 0xFFFF0000u);
  f[6] = __uint_as_float(u.w << 16); f[7] = __uint_as_float(u.w & 0xFFFF0000u);
}

// ---------------- conversion kernels ----------------
__global__ __launch_bounds__(256) void cvt_x_kernel(const float* __restrict__ x,
                                                    unsigned short* __restrict__ o){
  int i = blockIdx.x * 256 + threadIdx.x;
  float4 f = ((const float4*)x)[i];
  ushort4v r;
  r[0] = f2bf(f.x); r[1] = f2bf(f.y); r[2] = f2bf(f.z); r[3] = f2bf(f.w);
  ((ushort4v*)o)[i] = r;
}

__global__ __launch_bounds__(256) void cvt_w_kernel(const float* __restrict__ Wq,
                                                    const float* __restrict__ Wk,
                                                    const float* __restrict__ Wv,
                                                    const float* __restrict__ Ws,
                                                    unsigned short* __restrict__ B){
  int i = blockIdx.x * 256 + threadIdx.x;
  int which = i >> 18;
  const float* src = (which == 0) ? Wq : (which == 1) ? Wk : (which == 2) ? Wv : Ws;
  float4 f = ((const float4*)src)[i & 262143];
  ushort4v r;
  r[0] = f2bf(f.x); r[1] = f2bf(f.y); r[2] = f2bf(f.z); r[3] = f2bf(f.w);
  ((ushort4v*)B)[i] = r;
}

__global__ void wb_prep_kernel(const float* __restrict__ Wb,
                               float* __restrict__ wba, float* __restrict__ wbb){
  int e = blockIdx.x * 256 + threadIdx.x;
  if (e < 1024){
    wba[e] = Wb[e]        + Wb[2048 + e];
    wbb[e] = Wb[1024 + e] - Wb[2048 + e];
  }
}

// masks -> bf16 {0,1} planes (written into dead xbf/bm workspace, after gemm)
__global__ __launch_bounds__(256) void mask_prep_kernel(const int* __restrict__ m,
                                                        const int* __restrict__ wm,
                                                        unsigned short* __restrict__ mb,
                                                        unsigned short* __restrict__ wb){
  int i = blockIdx.x * 256 + threadIdx.x;
  const int4* mp = (const int4*)(m + (size_t)i * 8);
  const int4* wp = (const int4*)(wm + (size_t)i * 8);
  int4 a0 = mp[0], a1 = mp[1], b0 = wp[0], b1 = wp[1];
  short8 rm, rw;
  rm[0] = a0.x ? 0x3F80 : 0; rm[1] = a0.y ? 0x3F80 : 0;
  rm[2] = a0.z ? 0x3F80 : 0; rm[3] = a0.w ? 0x3F80 : 0;
  rm[4] = a1.x ? 0x3F80 : 0; rm[5] = a1.y ? 0x3F80 : 0;
  rm[6] = a1.z ? 0x3F80 : 0; rm[7] = a1.w ? 0x3F80 : 0;
  rw[0] = b0.x ? 0x3F80 : 0; rw[1] = b0.y ? 0x3F80 : 0;
  rw[2] = b0.z ? 0x3F80 : 0; rw[3] = b0.w ? 0x3F80 : 0;
  rw[4] = b1.x ? 0x3F80 : 0; rw[5] = b1.y ? 0x3F80 : 0;
  rw[6] = b1.z ? 0x3F80 : 0; rw[7] = b1.w ? 0x3F80 : 0;
  ((short8*)mb)[i] = rm;
  ((short8*)wb)[i] = rw;
}

// ---------------- fused projection GEMM ----------------
__global__ __launch_bounds__(256, 2) void gemm_proj_kernel(
    const unsigned short* __restrict__ X, const unsigned short* __restrict__ B,
    unsigned short* __restrict__ qb, unsigned short* __restrict__ kb,
    unsigned short* __restrict__ vT, float* __restrict__ rb)
{
  __shared__ unsigned short As[128 * 32];
  __shared__ unsigned short Bs[128 * 32];
  const int tid = threadIdx.x;
  const int w = tid >> 6, l = tid & 63;
  const int lr = l & 15, lq = l >> 4;
  const int wr = w >> 1, wc = w & 1;
  const int bid = ((blockIdx.x & 7) << 8) | (blockIdx.x >> 3);   // XCD swizzle (2048 = 8*256)
  const int m0 = (bid >> 5) * 128;
  const int n0 = (bid & 31) * 128;
  f32x4 acc[4][4] = {};

  for (int k0 = 0; k0 < 1024; k0 += 32){
    #pragma unroll
    for (int i = 0; i < 2; i++){
      int c = i * 256 + tid;
      gload_lds16(X + (size_t)(m0 + (c >> 2)) * 1024 + k0 + (c & 3) * 8,
                  As + (i * 256 + w * 64) * 8);
      gload_lds16(B + (size_t)(n0 + (c >> 2)) * 1024 + k0 + (c & 3) * 8,
                  Bs + (i * 256 + w * 64) * 8);
    }
    __syncthreads();
    short8 av[4], bv[4];
    #pragma unroll
    for (int mf = 0; mf < 4; mf++)
      av[mf] = *(const short8*)(As + (wr * 64 + mf * 16 + lr) * 32 + lq * 8);
    #pragma unroll
    for (int nf = 0; nf < 4; nf++)
      bv[nf] = *(const short8*)(Bs + (wc * 64 + nf * 16 + lr) * 32 + lq * 8);
    #pragma unroll
    for (int mf = 0; mf < 4; mf++)
      #pragma unroll
      for (int nf = 0; nf < 4; nf++)
        acc[mf][nf] = MFMA_BF16(av[mf], bv[nf], acc[mf][nf]);
    __syncthreads();
  }

  const int which = (n0 >> 10);
  #pragma unroll
  for (int mf = 0; mf < 4; mf++){
    #pragma unroll
    for (int nf = 0; nf < 4; nf++){
      const int col = n0 + wc * 64 + nf * 16 + lr;
      const int o = col & 1023;
      #pragma unroll
      for (int rg = 0; rg < 4; rg++){
        const int rowi = m0 + wr * 64 + mf * 16 + lq * 4 + rg;
        const float val = acc[mf][nf][rg];
        if (which == 3){
          rb[(size_t)rowi * 1024 + o] = val;
        } else {
          const int s = rowi >> 4, bb = rowi & 15;
          const int bh = bb * 16 + (o >> 6), d = o & 63;
          if (which == 0)      qb[((size_t)bh * 512 + s) * 64 + d] = f2bf(val);
          else if (which == 1) kb[((size_t)bh * 512 + s) * 64 + d] = f2bf(val);
          else                 vT[((size_t)bh * 64 + d) * 512 + s] = f2bf(val);
        }
      }
    }
  }
}

// ---------------- fused attention ----------------
// 16 q-rows/block, 4 waves, 8192 blocks.
// Phase A: wave w computes e1 = exp(s/8) for k-slice [128w,128w+128), bf16 -> sE.
// Phase B: wave w owns rows 4w..4w+3 full-width; 4-row-interleaved shuffle reductions.
// Phase C: wave w computes out d-frag [16w,16w+16) over full k=512; direct global store.
__global__ __launch_bounds__(256, 4) void attn_kernel(
    const unsigned short* __restrict__ qg, const unsigned short* __restrict__ kg,
    const unsigned short* __restrict__ vt,
    const unsigned short* __restrict__ mbf, const unsigned short* __restrict__ wbf,
    float* __restrict__ outp)
{
  __shared__ __align__(16) unsigned short sE[16 * 520];   // e1 -> attn weights (in-place)
  __shared__ float sfin[16];
  const int bid = ((blockIdx.x & 7) << 10) | (blockIdx.x >> 3);  // XCD swizzle (8192 = 8*1024)
  const int qt = bid & 31, h = (bid >> 5) & 15, b = bid >> 9;
  const int bh = b * 16 + h;
  const int tid = threadIdx.x, w = tid >> 6, l = tid & 63;
  const int lr = l & 15, lq = l >> 4;
  const unsigned short* qp = qg + ((size_t)bh * 512 + qt * 16) * 64;
  const unsigned short* kp = kg + (size_t)bh * 512 * 64;
  const unsigned short* vp = vt + (size_t)bh * 64 * 512;

  // ---- Phase A: QK^T over this wave's 128-col k-slice, exp -> bf16 LDS ----
  short8 qa0 = *(const short8*)(qp + lr * 64 + lq * 8);
  short8 qa1 = *(const short8*)(qp + lr * 64 + 32 + lq * 8);
  f32x4 acc[8];
  #pragma unroll
  for (int kf = 0; kf < 8; kf++){
    const unsigned short* kr = kp + (size_t)(w * 128 + kf * 16 + lr) * 64;
    short8 k0 = *(const short8*)(kr + lq * 8);
    short8 k1 = *(const short8*)(kr + 32 + lq * 8);
    f32x4 a = {};
    a = MFMA_BF16(qa0, k0, a);
    a = MFMA_BF16(qa1, k1, a);
    acc[kf] = a;
  }
  const float CEXP = 0.18033688011112042f;   // 0.125 * log2(e)
  #pragma unroll
  for (int kf = 0; kf < 8; kf++){
    float a0 = __builtin_amdgcn_exp2f(acc[kf][0] * CEXP);
    float a1 = __builtin_amdgcn_exp2f(acc[kf][1] * CEXP);
    float a2 = __builtin_amdgcn_exp2f(acc[kf][2] * CEXP);
    float a3 = __builtin_amdgcn_exp2f(acc[kf][3] * CEXP);
    unsigned int p01 = cvtpk(a0, a1), p23 = cvtpk(a2, a3);
    const int row = lq * 4;
    const int col = w * 128 + kf * 16 + lr;
    sE[(row    ) * 520 + col] = (unsigned short)(p01 & 0xFFFFu);
    sE[(row + 1) * 520 + col] = (unsigned short)(p01 >> 16);
    sE[(row + 2) * 520 + col] = (unsigned short)(p23 & 0xFFFFu);
    sE[(row + 3) * 520 + col] = (unsigned short)(p23 >> 16);
  }

  // hoist Phase-B mask loads: latency hides under the barrier
  uint4 mu[4], wu[4];
  #pragma unroll
  for (int rr = 0; rr < 4; rr++){
    const int qrow = qt * 16 + w * 4 + rr;
    mu[rr] = *(const uint4*)(mbf + ((size_t)b * 512 + qrow) * 512 + l * 8);
    wu[rr] = *(const uint4*)(wbf + ((size_t)b * 512 + qrow) * 512 + l * 8);
  }
  __syncthreads();

  // ---- Phase B: double masked softmax, 4 rows per wave, interleaved chains ----
  {
    uint4 ev[4];
    #pragma unroll
    for (int rr = 0; rr < 4; rr++)
      ev[rr] = *(const uint4*)(sE + (w * 4 + rr) * 520 + l * 8);

    float em[4][8]; float z1[4];
    #pragma unroll
    for (int rr = 0; rr < 4; rr++){
      float e1[8], mf[8];
      unpack8(ev[rr], e1); unpack8(mu[rr], mf);
      float z = 0.f;
      #pragma unroll
      for (int j = 0; j < 8; j++){ em[rr][j] = e1[j] * mf[j]; z += em[rr][j]; }
      z1[rr] = z;
    }
    #pragma unroll
    for (int m = 32; m; m >>= 1){
      #pragma unroll
      for (int rr = 0; rr < 4; rr++) z1[rr] += __shfl_xor(z1[rr], m, 64);
    }
    float e2[4][8]; float z2[4];
    #pragma unroll
    for (int rr = 0; rr < 4; rr++){
      const float i1L = 1.4426950408889634f / z1[rr];
      float wf[8];
      unpack8(wu[rr], wf);
      float z = 0.f;
      #pragma unroll
      for (int j = 0; j < 8; j++){
        e2[rr][j] = __builtin_amdgcn_exp2f(em[rr][j] * i1L) * wf[j];
        z += e2[rr][j];
      }
      z2[rr] = z;
    }
    #pragma unroll
    for (int m = 32; m; m >>= 1){
      #pragma unroll
      for (int rr = 0; rr < 4; rr++) z2[rr] += __shfl_xor(z2[rr], m, 64);
    }
    #pragma unroll
    for (int rr = 0; rr < 4; rr++){
      uint4 o;
      o.x = cvtpk(e2[rr][0], e2[rr][1]); o.y = cvtpk(e2[rr][2], e2[rr][3]);
      o.z = cvtpk(e2[rr][4], e2[rr][5]); o.w = cvtpk(e2[rr][6], e2[rr][7]);
      *(uint4*)(sE + (w * 4 + rr) * 520 + l * 8) = o;
      if (l == 0) sfin[w * 4 + rr] = 1.f / (z2[rr] + 1e-10f);
    }
  }
  __syncthreads();

  // ---- Phase C: out d-frag [16w,16w+16) over full k, direct store ----
  {
    f32x4 po = {};
    #pragma unroll
    for (int ks = 0; ks < 16; ks++){
      short8 af = *(const short8*)(sE + lr * 520 + ks * 32 + lq * 8);
      short8 vf = *(const short8*)(vp + (size_t)(w * 16 + lr) * 512 + ks * 32 + lq * 8);
      po = MFMA_BF16(af, vf, po);
    }
    #pragma unroll
    for (int rg = 0; rg < 4; rg++){
      const int row = lq * 4 + rg;
      outp[((size_t)(qt * 16 + row) * 16 + b) * 1024 + h * 64 + w * 16 + lr]
          = po[rg] * sfin[row];
    }
  }
}

// ---------------- gate + mix ----------------
__global__ __launch_bounds__(256) void gate_kernel(
    const float* __restrict__ outp, const float* __restrict__ rb,
    const float* __restrict__ wba, const float* __restrict__ wbb,
    float* __restrict__ y)
{
  const int t = blockIdx.x * 4 + (threadIdx.x >> 6);
  const int l = threadIdx.x & 63;
  const float* o = outp + (size_t)t * 1024;
  const float* r = rb + (size_t)t * 1024;
  float ov[16], rv[16];
  float acc = 0.f;
  #pragma unroll
  for (int j = 0; j < 16; j++){
    const int e = j * 64 + l;
    ov[j] = o[e]; rv[j] = r[e];
    acc += ov[j] * wba[e] + rv[j] * wbb[e];
  }
  const float dot = wred_sum(acc);
  const float g = 1.f / (1.f + __builtin_amdgcn_exp2f(-dot * 1.4426950408889634f));
  float* yo = y + (size_t)t * 1024;
  #pragma unroll
  for (int j = 0; j < 16; j++){
    const int e = j * 64 + l;
    yo[e] = g * rv[j] + (1.f - g) * ov[j];
  }
}

// ---------------- launch ----------------
extern "C" void kernel_launch(void* const* d_in, const int* in_sizes, int n_in,
                              void* d_out, int out_size, void* d_ws, size_t ws_size,
                              hipStream_t stream)
{
  (void)in_sizes; (void)n_in; (void)out_size; (void)ws_size;
  const float* x   = (const float*)d_in[0];
  const int* mask  = (const int*)d_in[1];
  const int* wmask = (const int*)d_in[2];
  const float* Wq  = (const float*)d_in[3];
  const float* Wk  = (const float*)d_in[4];
  const float* Wv  = (const float*)d_in[5];
  const float* Ws  = (const float*)d_in[6];
  const float* Wb  = (const float*)d_in[7];

  char* ws = (char*)d_ws;
  unsigned short* xbf = (unsigned short*)ws; ws += 16777216;
  unsigned short* bm  = (unsigned short*)ws; ws += 8388608;
  unsigned short* qb  = (unsigned short*)ws; ws += 16777216;
  unsigned short* kb  = (unsigned short*)ws; ws += 16777216;
  unsigned short* vT  = (unsigned short*)ws; ws += 16777216;
  float* rb  = (float*)ws; ws += 33554432;
  float* op  = (float*)ws; ws += 33554432;
  float* wba = (float*)ws; ws += 4096;
  float* wbb = (float*)ws; ws += 4096;
  // mask bf16 planes reuse xbf (8.39MB of 16MB) and bm (8.39MB) after gemm
  unsigned short* mbf = xbf;
  unsigned short* wbf = bm;

  cvt_x_kernel<<<8192, 256, 0, stream>>>(x, xbf);
  cvt_w_kernel<<<4096, 256, 0, stream>>>(Wq, Wk, Wv, Ws, bm);
  wb_prep_kernel<<<4, 256, 0, stream>>>(Wb, wba, wbb);
  gemm_proj_kernel<<<2048, 256, 0, stream>>>(xbf, bm, qb, kb, vT, rb);
  mask_prep_kernel<<<2048, 256, 0, stream>>>(mask, wmask, mbf, wbf);
  attn_kernel<<<8192, 256, 0, stream>>>(qb, kb, vT, mbf, wbf, op);
  gate_kernel<<<2048, 256, 0, stream>>>(op, rb, wba, wbb, (float*)d_out);
}

// Round 5
// 268.305 us; speedup vs baseline: 2.2048x; 1.1831x over previous
//
#include <hip/hip_runtime.h>
#include <hip/hip_bf16.h>
#include <stdint.h>

typedef __attribute__((ext_vector_type(8))) short short8;
typedef __attribute__((ext_vector_type(4))) float f32x4;
typedef __attribute__((ext_vector_type(4))) unsigned short ushort4v;

#define MFMA_BF16(a,b,c) __builtin_amdgcn_mfma_f32_16x16x32_bf16((a),(b),(c),0,0,0)

static __device__ __forceinline__ unsigned short f2bf(float f){
  union { float fv; unsigned int u; } c; c.fv = f;
  unsigned int u = c.u;
  return (unsigned short)((u + 0x7fffu + ((u >> 16) & 1u)) >> 16);
}

static __device__ __forceinline__ unsigned int cvtpk(float a, float b){
  unsigned int r;
  asm("v_cvt_pk_bf16_f32 %0, %1, %2" : "=v"(r) : "v"(a), "v"(b));
  return r;
}

static __device__ __forceinline__ void gload_lds16(const void* g, void* l){
  __builtin_amdgcn_global_load_lds(
      (const __attribute__((address_space(1))) void*)g,
      (__attribute__((address_space(3))) void*)l, 16, 0, 0);
}

static __device__ __forceinline__ float wred_sum(float v){
  #pragma unroll
  for (int m = 32; m; m >>= 1) v += __shfl_xor(v, m, 64);
  return v;
}

static __device__ __forceinline__ void unpack8(uint4 u, float* f){
  f[0] = __uint_as_float(u.x << 16); f[1] = __uint_as_float(u.x & 0xFFFF0000u);
  f[2] = __uint_as_float(u.y << 16); f[3] = __uint_as_float(u.y & 0xFFFF0000u);
  f[4] = __uint_as_float(u.z << 16); f[5] = __uint_as_float(u.z & 0xFFFF0000u);
  f[6] = __uint_as_float(u.w << 16); f[7] = __uint_as_float(u.w & 0xFFFF0000u);
}

// ---------------- conversion kernels ----------------
__global__ __launch_bounds__(256) void cvt_x_kernel(const float* __restrict__ x,
                                                    unsigned short* __restrict__ o){
  int i = blockIdx.x * 256 + threadIdx.x;
  float4 f = ((const float4*)x)[i];
  ushort4v r;
  r[0] = f2bf(f.x); r[1] = f2bf(f.y); r[2] = f2bf(f.z); r[3] = f2bf(f.w);
  ((ushort4v*)o)[i] = r;
}

__global__ __launch_bounds__(256) void cvt_w_kernel(const float* __restrict__ Wq,
                                                    const float* __restrict__ Wk,
                                                    const float* __restrict__ Wv,
                                                    const float* __restrict__ Ws,
                                                    unsigned short* __restrict__ B){
  int i = blockIdx.x * 256 + threadIdx.x;
  int which = i >> 18;
  const float* src = (which == 0) ? Wq : (which == 1) ? Wk : (which == 2) ? Wv : Ws;
  float4 f = ((const float4*)src)[i & 262143];
  ushort4v r;
  r[0] = f2bf(f.x); r[1] = f2bf(f.y); r[2] = f2bf(f.z); r[3] = f2bf(f.w);
  ((ushort4v*)B)[i] = r;
}

__global__ void wb_prep_kernel(const float* __restrict__ Wb,
                               float* __restrict__ wba, float* __restrict__ wbb){
  int e = blockIdx.x * 256 + threadIdx.x;
  if (e < 1024){
    wba[e] = Wb[e]        + Wb[2048 + e];
    wbb[e] = Wb[1024 + e] - Wb[2048 + e];
  }
}

// masks -> bf16 {0,1} planes (written into dead xbf/bm workspace, after gemm)
__global__ __launch_bounds__(256) void mask_prep_kernel(const int* __restrict__ m,
                                                        const int* __restrict__ wm,
                                                        unsigned short* __restrict__ mb,
                                                        unsigned short* __restrict__ wb){
  int i = blockIdx.x * 256 + threadIdx.x;
  const int4* mp = (const int4*)(m + (size_t)i * 8);
  const int4* wp = (const int4*)(wm + (size_t)i * 8);
  int4 a0 = mp[0], a1 = mp[1], b0 = wp[0], b1 = wp[1];
  short8 rm, rw;
  rm[0] = a0.x ? 0x3F80 : 0; rm[1] = a0.y ? 0x3F80 : 0;
  rm[2] = a0.z ? 0x3F80 : 0; rm[3] = a0.w ? 0x3F80 : 0;
  rm[4] = a1.x ? 0x3F80 : 0; rm[5] = a1.y ? 0x3F80 : 0;
  rm[6] = a1.z ? 0x3F80 : 0; rm[7] = a1.w ? 0x3F80 : 0;
  rw[0] = b0.x ? 0x3F80 : 0; rw[1] = b0.y ? 0x3F80 : 0;
  rw[2] = b0.z ? 0x3F80 : 0; rw[3] = b0.w ? 0x3F80 : 0;
  rw[4] = b1.x ? 0x3F80 : 0; rw[5] = b1.y ? 0x3F80 : 0;
  rw[6] = b1.z ? 0x3F80 : 0; rw[7] = b1.w ? 0x3F80 : 0;
  ((short8*)mb)[i] = rm;
  ((short8*)wb)[i] = rw;
}

// ---------------- fused projection GEMM ----------------
// C(8192 x 4096) = Xbf @ Bmat^T; epilogue stages C-tile in LDS for coalesced
// 16B stores: q/k (b,h,s,d), v transposed (b,h,d,s), r (t,e) fp32 direct.
__global__ __launch_bounds__(256, 3) void gemm_proj_kernel(
    const unsigned short* __restrict__ X, const unsigned short* __restrict__ B,
    unsigned short* __restrict__ qb, unsigned short* __restrict__ kb,
    unsigned short* __restrict__ vT, float* __restrict__ rb)
{
  __shared__ __align__(16) unsigned short smem[128 * 136];   // As(4096)+Bs(4096) alias C-tile
  unsigned short* As = smem;
  unsigned short* Bs = smem + 4096;
  const int tid = threadIdx.x;
  const int w = tid >> 6, l = tid & 63;
  const int lr = l & 15, lq = l >> 4;
  const int wr = w >> 1, wc = w & 1;
  const int bid = ((blockIdx.x & 7) << 8) | (blockIdx.x >> 3);   // XCD swizzle (2048 = 8*256)
  const int m0 = (bid >> 5) * 128;
  const int n0 = (bid & 31) * 128;
  f32x4 acc[4][4] = {};

  for (int k0 = 0; k0 < 1024; k0 += 32){
    #pragma unroll
    for (int i = 0; i < 2; i++){
      int c = i * 256 + tid;
      gload_lds16(X + (size_t)(m0 + (c >> 2)) * 1024 + k0 + (c & 3) * 8,
                  As + (i * 256 + w * 64) * 8);
      gload_lds16(B + (size_t)(n0 + (c >> 2)) * 1024 + k0 + (c & 3) * 8,
                  Bs + (i * 256 + w * 64) * 8);
    }
    __syncthreads();
    short8 av[4], bv[4];
    #pragma unroll
    for (int mf = 0; mf < 4; mf++)
      av[mf] = *(const short8*)(As + (wr * 64 + mf * 16 + lr) * 32 + lq * 8);
    #pragma unroll
    for (int nf = 0; nf < 4; nf++)
      bv[nf] = *(const short8*)(Bs + (wc * 64 + nf * 16 + lr) * 32 + lq * 8);
    #pragma unroll
    for (int mf = 0; mf < 4; mf++)
      #pragma unroll
      for (int nf = 0; nf < 4; nf++)
        acc[mf][nf] = MFMA_BF16(av[mf], bv[nf], acc[mf][nf]);
    __syncthreads();
  }

  const int which = (n0 >> 10);
  if (which == 3){
    // r: fp32 direct stores (16-lane 64B runs, full sectors)
    #pragma unroll
    for (int mf = 0; mf < 4; mf++)
      #pragma unroll
      for (int nf = 0; nf < 4; nf++){
        const int o = (n0 & 1023) + wc * 64 + nf * 16 + lr;
        #pragma unroll
        for (int rg = 0; rg < 4; rg++){
          const int rowi = m0 + wr * 64 + mf * 16 + lq * 4 + rg;
          rb[(size_t)rowi * 1024 + o] = acc[mf][nf][rg];
        }
      }
  } else if (which == 2){
    // v: transposed LDS staging [col][row], stride 132, packed b64 writes
    #pragma unroll
    for (int mf = 0; mf < 4; mf++)
      #pragma unroll
      for (int nf = 0; nf < 4; nf++){
        const int r0 = wr * 64 + mf * 16 + lq * 4;
        const int c  = wc * 64 + nf * 16 + lr;
        uint2 pk;
        pk.x = cvtpk(acc[mf][nf][0], acc[mf][nf][1]);
        pk.y = cvtpk(acc[mf][nf][2], acc[mf][nf][3]);
        *(uint2*)(smem + c * 132 + r0) = pk;
      }
    __syncthreads();
    const int s0 = m0 >> 4;                    // 8 consecutive s per tile
    #pragma unroll
    for (int p = 0; p < 8; p++){
      const int cid = p * 256 + tid;
      const int c = cid >> 4, bb = cid & 15;
      short8 st;
      #pragma unroll
      for (int j = 0; j < 8; j++) st[j] = (short)smem[c * 132 + j * 16 + bb];
      const int o = (n0 & 1023) + c;
      const int bh = bb * 16 + (o >> 6), d = o & 63;
      *(short8*)(vT + ((size_t)bh * 64 + d) * 512 + s0) = st;
    }
  } else {
    // q/k: row-major LDS staging [row][col], stride 136, b128 reads + 16B stores
    #pragma unroll
    for (int mf = 0; mf < 4; mf++)
      #pragma unroll
      for (int nf = 0; nf < 4; nf++)
        #pragma unroll
        for (int rg = 0; rg < 4; rg++)
          smem[(wr * 64 + mf * 16 + lq * 4 + rg) * 136 + wc * 64 + nf * 16 + lr]
              = f2bf(acc[mf][nf][rg]);
    __syncthreads();
    unsigned short* dst = (which == 0) ? qb : kb;
    #pragma unroll
    for (int p = 0; p < 8; p++){
      const int cid = p * 256 + tid;
      const int lrow = cid >> 4, cg = cid & 15;
      short8 vv = *(const short8*)(smem + lrow * 136 + cg * 8);
      const int rowi = m0 + lrow;
      const int s = rowi >> 4, bb = rowi & 15;
      const int o = (n0 & 1023) + cg * 8;
      const int bh = bb * 16 + (o >> 6), d = o & 63;
      *(short8*)(dst + ((size_t)bh * 512 + s) * 64 + d) = vv;
    }
  }
}

// ---------------- fused attention ----------------
// 16 q-rows/block, 4 waves, 8192 blocks.
__global__ __launch_bounds__(256, 4) void attn_kernel(
    const unsigned short* __restrict__ qg, const unsigned short* __restrict__ kg,
    const unsigned short* __restrict__ vt,
    const unsigned short* __restrict__ mbf, const unsigned short* __restrict__ wbf,
    float* __restrict__ outp)
{
  __shared__ __align__(16) unsigned short sE[16 * 520];   // e1 -> attn weights (in-place)
  __shared__ float sfin[16];
  const int bid = ((blockIdx.x & 7) << 10) | (blockIdx.x >> 3);  // XCD swizzle (8192 = 8*1024)
  const int qt = bid & 31, h = (bid >> 5) & 15, b = bid >> 9;
  const int bh = b * 16 + h;
  const int tid = threadIdx.x, w = tid >> 6, l = tid & 63;
  const int lr = l & 15, lq = l >> 4;
  const unsigned short* qp = qg + ((size_t)bh * 512 + qt * 16) * 64;
  const unsigned short* kp = kg + (size_t)bh * 512 * 64;
  const unsigned short* vp = vt + (size_t)bh * 64 * 512;

  // ---- Phase A: QK^T over this wave's 128-col k-slice, exp -> bf16 LDS ----
  short8 qa0 = *(const short8*)(qp + lr * 64 + lq * 8);
  short8 qa1 = *(const short8*)(qp + lr * 64 + 32 + lq * 8);
  f32x4 acc[8];
  #pragma unroll
  for (int kf = 0; kf < 8; kf++){
    const unsigned short* kr = kp + (size_t)(w * 128 + kf * 16 + lr) * 64;
    short8 k0 = *(const short8*)(kr + lq * 8);
    short8 k1 = *(const short8*)(kr + 32 + lq * 8);
    f32x4 a = {};
    a = MFMA_BF16(qa0, k0, a);
    a = MFMA_BF16(qa1, k1, a);
    acc[kf] = a;
  }
  const float CEXP = 0.18033688011112042f;   // 0.125 * log2(e)
  #pragma unroll
  for (int kf = 0; kf < 8; kf++){
    float a0 = __builtin_amdgcn_exp2f(acc[kf][0] * CEXP);
    float a1 = __builtin_amdgcn_exp2f(acc[kf][1] * CEXP);
    float a2 = __builtin_amdgcn_exp2f(acc[kf][2] * CEXP);
    float a3 = __builtin_amdgcn_exp2f(acc[kf][3] * CEXP);
    unsigned int p01 = cvtpk(a0, a1), p23 = cvtpk(a2, a3);
    const int row = lq * 4;
    const int col = w * 128 + kf * 16 + lr;
    sE[(row    ) * 520 + col] = (unsigned short)(p01 & 0xFFFFu);
    sE[(row + 1) * 520 + col] = (unsigned short)(p01 >> 16);
    sE[(row + 2) * 520 + col] = (unsigned short)(p23 & 0xFFFFu);
    sE[(row + 3) * 520 + col] = (unsigned short)(p23 >> 16);
  }

  // hoist Phase-B mask loads: latency hides under the barrier
  uint4 mu[4], wu[4];
  #pragma unroll
  for (int rr = 0; rr < 4; rr++){
    const int qrow = qt * 16 + w * 4 + rr;
    mu[rr] = *(const uint4*)(mbf + ((size_t)b * 512 + qrow) * 512 + l * 8);
    wu[rr] = *(const uint4*)(wbf + ((size_t)b * 512 + qrow) * 512 + l * 8);
  }
  __syncthreads();

  // ---- Phase B: double masked softmax, 4 rows per wave, interleaved chains ----
  {
    uint4 ev[4];
    #pragma unroll
    for (int rr = 0; rr < 4; rr++)
      ev[rr] = *(const uint4*)(sE + (w * 4 + rr) * 520 + l * 8);

    float em[4][8]; float z1[4];
    #pragma unroll
    for (int rr = 0; rr < 4; rr++){
      float e1[8], mf[8];
      unpack8(ev[rr], e1); unpack8(mu[rr], mf);
      float z = 0.f;
      #pragma unroll
      for (int j = 0; j < 8; j++){ em[rr][j] = e1[j] * mf[j]; z += em[rr][j]; }
      z1[rr] = z;
    }
    #pragma unroll
    for (int m = 32; m; m >>= 1){
      #pragma unroll
      for (int rr = 0; rr < 4; rr++) z1[rr] += __shfl_xor(z1[rr], m, 64);
    }
    float e2[4][8]; float z2[4];
    #pragma unroll
    for (int rr = 0; rr < 4; rr++){
      const float i1L = 1.4426950408889634f / z1[rr];
      float wf[8];
      unpack8(wu[rr], wf);
      float z = 0.f;
      #pragma unroll
      for (int j = 0; j < 8; j++){
        e2[rr][j] = __builtin_amdgcn_exp2f(em[rr][j] * i1L) * wf[j];
        z += e2[rr][j];
      }
      z2[rr] = z;
    }
    #pragma unroll
    for (int m = 32; m; m >>= 1){
      #pragma unroll
      for (int rr = 0; rr < 4; rr++) z2[rr] += __shfl_xor(z2[rr], m, 64);
    }
    #pragma unroll
    for (int rr = 0; rr < 4; rr++){
      uint4 o;
      o.x = cvtpk(e2[rr][0], e2[rr][1]); o.y = cvtpk(e2[rr][2], e2[rr][3]);
      o.z = cvtpk(e2[rr][4], e2[rr][5]); o.w = cvtpk(e2[rr][6], e2[rr][7]);
      *(uint4*)(sE + (w * 4 + rr) * 520 + l * 8) = o;
      if (l == 0) sfin[w * 4 + rr] = 1.f / (z2[rr] + 1e-10f);
    }
  }
  __syncthreads();

  // ---- Phase C: out d-frag [16w,16w+16) over full k, direct store ----
  {
    f32x4 po = {};
    #pragma unroll
    for (int ks = 0; ks < 16; ks++){
      short8 af = *(const short8*)(sE + lr * 520 + ks * 32 + lq * 8);
      short8 vf = *(const short8*)(vp + (size_t)(w * 16 + lr) * 512 + ks * 32 + lq * 8);
      po = MFMA_BF16(af, vf, po);
    }
    #pragma unroll
    for (int rg = 0; rg < 4; rg++){
      const int row = lq * 4 + rg;
      outp[((size_t)(qt * 16 + row) * 16 + b) * 1024 + h * 64 + w * 16 + lr]
          = po[rg] * sfin[row];
    }
  }
}

// ---------------- gate + mix ----------------
__global__ __launch_bounds__(256) void gate_kernel(
    const float* __restrict__ outp, const float* __restrict__ rb,
    const float* __restrict__ wba, const float* __restrict__ wbb,
    float* __restrict__ y)
{
  const int t = blockIdx.x * 4 + (threadIdx.x >> 6);
  const int l = threadIdx.x & 63;
  const float* o = outp + (size_t)t * 1024;
  const float* r = rb + (size_t)t * 1024;
  float ov[16], rv[16];
  float acc = 0.f;
  #pragma unroll
  for (int j = 0; j < 16; j++){
    const int e = j * 64 + l;
    ov[j] = o[e]; rv[j] = r[e];
    acc += ov[j] * wba[e] + rv[j] * wbb[e];
  }
  const float dot = wred_sum(acc);
  const float g = 1.f / (1.f + __builtin_amdgcn_exp2f(-dot * 1.4426950408889634f));
  float* yo = y + (size_t)t * 1024;
  #pragma unroll
  for (int j = 0; j < 16; j++){
    const int e = j * 64 + l;
    yo[e] = g * rv[j] + (1.f - g) * ov[j];
  }
}

// ---------------- launch ----------------
extern "C" void kernel_launch(void* const* d_in, const int* in_sizes, int n_in,
                              void* d_out, int out_size, void* d_ws, size_t ws_size,
                              hipStream_t stream)
{
  (void)in_sizes; (void)n_in; (void)out_size; (void)ws_size;
  const float* x   = (const float*)d_in[0];
  const int* mask  = (const int*)d_in[1];
  const int* wmask = (const int*)d_in[2];
  const float* Wq  = (const float*)d_in[3];
  const float* Wk  = (const float*)d_in[4];
  const float* Wv  = (const float*)d_in[5];
  const float* Ws  = (const float*)d_in[6];
  const float* Wb  = (const float*)d_in[7];

  char* ws = (char*)d_ws;
  unsigned short* xbf = (unsigned short*)ws; ws += 16777216;
  unsigned short* bm  = (unsigned short*)ws; ws += 8388608;
  unsigned short* qb  = (unsigned short*)ws; ws += 16777216;
  unsigned short* kb  = (unsigned short*)ws; ws += 16777216;
  unsigned short* vT  = (unsigned short*)ws; ws += 16777216;
  float* rb  = (float*)ws; ws += 33554432;
  float* op  = (float*)ws; ws += 33554432;
  float* wba = (float*)ws; ws += 4096;
  float* wbb = (float*)ws; ws += 4096;
  // mask bf16 planes reuse xbf (8.39MB of 16MB) and bm (8.39MB) after gemm
  unsigned short* mbf = xbf;
  unsigned short* wbf = bm;

  cvt_x_kernel<<<8192, 256, 0, stream>>>(x, xbf);
  cvt_w_kernel<<<4096, 256, 0, stream>>>(Wq, Wk, Wv, Ws, bm);
  wb_prep_kernel<<<4, 256, 0, stream>>>(Wb, wba, wbb);
  gemm_proj_kernel<<<2048, 256, 0, stream>>>(xbf, bm, qb, kb, vT, rb);
  mask_prep_kernel<<<2048, 256, 0, stream>>>(mask, wmask, mbf, wbf);
  attn_kernel<<<8192, 256, 0, stream>>>(qb, kb, vT, mbf, wbf, op);
  gate_kernel<<<2048, 256, 0, stream>>>(op, rb, wba, wbb, (float*)d_out);
}

// Round 6
// 263.105 us; speedup vs baseline: 2.2483x; 1.0198x over previous
//
#include <hip/hip_runtime.h>
#include <hip/hip_bf16.h>
#include <stdint.h>

typedef __attribute__((ext_vector_type(8))) short short8;
typedef __attribute__((ext_vector_type(4))) float f32x4;
typedef __attribute__((ext_vector_type(4))) unsigned short ushort4v;

#define MFMA_BF16(a,b,c) __builtin_amdgcn_mfma_f32_16x16x32_bf16((a),(b),(c),0,0,0)

static __device__ __forceinline__ unsigned short f2bf(float f){
  union { float fv; unsigned int u; } c; c.fv = f;
  unsigned int u = c.u;
  return (unsigned short)((u + 0x7fffu + ((u >> 16) & 1u)) >> 16);
}

static __device__ __forceinline__ unsigned int cvtpk(float a, float b){
  unsigned int r;
  asm("v_cvt_pk_bf16_f32 %0, %1, %2" : "=v"(r) : "v"(a), "v"(b));
  return r;
}

static __device__ __forceinline__ void gload_lds16(const void* g, void* l){
  __builtin_amdgcn_global_load_lds(
      (const __attribute__((address_space(1))) void*)g,
      (__attribute__((address_space(3))) void*)l, 16, 0, 0);
}

static __device__ __forceinline__ float wred_sum(float v){
  #pragma unroll
  for (int m = 32; m; m >>= 1) v += __shfl_xor(v, m, 64);
  return v;
}

static __device__ __forceinline__ void unpack8(uint4 u, float* f){
  f[0] = __uint_as_float(u.x << 16); f[1] = __uint_as_float(u.x & 0xFFFF0000u);
  f[2] = __uint_as_float(u.y << 16); f[3] = __uint_as_float(u.y & 0xFFFF0000u);
  f[4] = __uint_as_float(u.z << 16); f[5] = __uint_as_float(u.z & 0xFFFF0000u);
  f[6] = __uint_as_float(u.w << 16); f[7] = __uint_as_float(u.w & 0xFFFF0000u);
}

// ---------------- conversion kernels ----------------
__global__ __launch_bounds__(256) void cvt_x_kernel(const float* __restrict__ x,
                                                    unsigned short* __restrict__ o){
  int i = blockIdx.x * 256 + threadIdx.x;
  float4 f = ((const float4*)x)[i];
  ushort4v r;
  r[0] = f2bf(f.x); r[1] = f2bf(f.y); r[2] = f2bf(f.z); r[3] = f2bf(f.w);
  ((ushort4v*)o)[i] = r;
}

__global__ __launch_bounds__(256) void cvt_w_kernel(const float* __restrict__ Wq,
                                                    const float* __restrict__ Wk,
                                                    const float* __restrict__ Wv,
                                                    const float* __restrict__ Ws,
                                                    unsigned short* __restrict__ B){
  int i = blockIdx.x * 256 + threadIdx.x;
  int which = i >> 18;
  const float* src = (which == 0) ? Wq : (which == 1) ? Wk : (which == 2) ? Wv : Ws;
  float4 f = ((const float4*)src)[i & 262143];
  ushort4v r;
  r[0] = f2bf(f.x); r[1] = f2bf(f.y); r[2] = f2bf(f.z); r[3] = f2bf(f.w);
  ((ushort4v*)B)[i] = r;
}

__global__ void wb_prep_kernel(const float* __restrict__ Wb,
                               float* __restrict__ wba, float* __restrict__ wbb){
  int e = blockIdx.x * 256 + threadIdx.x;
  if (e < 1024){
    wba[e] = Wb[e]        + Wb[2048 + e];
    wbb[e] = Wb[1024 + e] - Wb[2048 + e];
  }
}

// masks -> bit planes via ballot: bit k of row bitmap = (mask[...,k] != 0)
__global__ __launch_bounds__(256) void mask_prep_kernel(
    const int* __restrict__ m, const int* __restrict__ wm,
    unsigned long long* __restrict__ mb, unsigned long long* __restrict__ wb)
{
  const size_t i = (size_t)blockIdx.x * 256 + threadIdx.x;
  const int a = m[i];
  const int c = wm[i];
  unsigned long long ba = __ballot(a != 0);
  unsigned long long bc = __ballot(c != 0);
  if ((threadIdx.x & 63) == 0){
    mb[i >> 6] = ba;
    wb[i >> 6] = bc;
  }
}

// ---------------- fused projection GEMM ----------------
// C(8192 x 4096) = Xbf @ Bmat^T; epilogue stages C-tile in LDS for coalesced
// 16B stores: q/k (b,h,s,d), v transposed (b,h,d,s), r (t,e) fp32 direct.
__global__ __launch_bounds__(256, 3) void gemm_proj_kernel(
    const unsigned short* __restrict__ X, const unsigned short* __restrict__ B,
    unsigned short* __restrict__ qb, unsigned short* __restrict__ kb,
    unsigned short* __restrict__ vT, float* __restrict__ rb)
{
  __shared__ __align__(16) unsigned short smem[128 * 136];   // As(4096)+Bs(4096) alias C-tile
  unsigned short* As = smem;
  unsigned short* Bs = smem + 4096;
  const int tid = threadIdx.x;
  const int w = tid >> 6, l = tid & 63;
  const int lr = l & 15, lq = l >> 4;
  const int wr = w >> 1, wc = w & 1;
  const int bid = ((blockIdx.x & 7) << 8) | (blockIdx.x >> 3);   // XCD swizzle (2048 = 8*256)
  const int m0 = (bid >> 5) * 128;
  const int n0 = (bid & 31) * 128;
  f32x4 acc[4][4] = {};

  for (int k0 = 0; k0 < 1024; k0 += 32){
    #pragma unroll
    for (int i = 0; i < 2; i++){
      int c = i * 256 + tid;
      gload_lds16(X + (size_t)(m0 + (c >> 2)) * 1024 + k0 + (c & 3) * 8,
                  As + (i * 256 + w * 64) * 8);
      gload_lds16(B + (size_t)(n0 + (c >> 2)) * 1024 + k0 + (c & 3) * 8,
                  Bs + (i * 256 + w * 64) * 8);
    }
    __syncthreads();
    short8 av[4], bv[4];
    #pragma unroll
    for (int mf = 0; mf < 4; mf++)
      av[mf] = *(const short8*)(As + (wr * 64 + mf * 16 + lr) * 32 + lq * 8);
    #pragma unroll
    for (int nf = 0; nf < 4; nf++)
      bv[nf] = *(const short8*)(Bs + (wc * 64 + nf * 16 + lr) * 32 + lq * 8);
    #pragma unroll
    for (int mf = 0; mf < 4; mf++)
      #pragma unroll
      for (int nf = 0; nf < 4; nf++)
        acc[mf][nf] = MFMA_BF16(av[mf], bv[nf], acc[mf][nf]);
    __syncthreads();
  }

  const int which = (n0 >> 10);
  if (which == 3){
    #pragma unroll
    for (int mf = 0; mf < 4; mf++)
      #pragma unroll
      for (int nf = 0; nf < 4; nf++){
        const int o = (n0 & 1023) + wc * 64 + nf * 16 + lr;
        #pragma unroll
        for (int rg = 0; rg < 4; rg++){
          const int rowi = m0 + wr * 64 + mf * 16 + lq * 4 + rg;
          rb[(size_t)rowi * 1024 + o] = acc[mf][nf][rg];
        }
      }
  } else if (which == 2){
    // v: transposed LDS staging [col][row], stride 132, packed b64 writes
    #pragma unroll
    for (int mf = 0; mf < 4; mf++)
      #pragma unroll
      for (int nf = 0; nf < 4; nf++){
        const int r0 = wr * 64 + mf * 16 + lq * 4;
        const int c  = wc * 64 + nf * 16 + lr;
        uint2 pk;
        pk.x = cvtpk(acc[mf][nf][0], acc[mf][nf][1]);
        pk.y = cvtpk(acc[mf][nf][2], acc[mf][nf][3]);
        *(uint2*)(smem + c * 132 + r0) = pk;
      }
    __syncthreads();
    const int s0 = m0 >> 4;                    // 8 consecutive s per tile
    #pragma unroll
    for (int p = 0; p < 8; p++){
      const int cid = p * 256 + tid;
      const int c = cid >> 4, bb = cid & 15;
      short8 st;
      #pragma unroll
      for (int j = 0; j < 8; j++) st[j] = (short)smem[c * 132 + j * 16 + bb];
      const int o = (n0 & 1023) + c;
      const int bh = bb * 16 + (o >> 6), d = o & 63;
      *(short8*)(vT + ((size_t)bh * 64 + d) * 512 + s0) = st;
    }
  } else {
    // q/k: row-major LDS staging [row][col], stride 136, b128 reads + 16B stores
    #pragma unroll
    for (int mf = 0; mf < 4; mf++)
      #pragma unroll
      for (int nf = 0; nf < 4; nf++)
        #pragma unroll
        for (int rg = 0; rg < 4; rg++)
          smem[(wr * 64 + mf * 16 + lq * 4 + rg) * 136 + wc * 64 + nf * 16 + lr]
              = f2bf(acc[mf][nf][rg]);
    __syncthreads();
    unsigned short* dst = (which == 0) ? qb : kb;
    #pragma unroll
    for (int p = 0; p < 8; p++){
      const int cid = p * 256 + tid;
      const int lrow = cid >> 4, cg = cid & 15;
      short8 vv = *(const short8*)(smem + lrow * 136 + cg * 8);
      const int rowi = m0 + lrow;
      const int s = rowi >> 4, bb = rowi & 15;
      const int o = (n0 & 1023) + cg * 8;
      const int bh = bb * 16 + (o >> 6), d = o & 63;
      *(short8*)(dst + ((size_t)bh * 512 + s) * 64 + d) = vv;
    }
  }
}

// ---------------- fused attention ----------------
// 16 q-rows/block, 4 waves, 8192 blocks. h-fastest ordering so the 16 blocks
// sharing mask rows are co-resident; bit-packed masks prefetched at kernel top.
__global__ __launch_bounds__(256, 4) void attn_kernel(
    const unsigned short* __restrict__ qg, const unsigned short* __restrict__ kg,
    const unsigned short* __restrict__ vt,
    const unsigned char* __restrict__ mbits, const unsigned char* __restrict__ wbits,
    float* __restrict__ outp)
{
  __shared__ __align__(16) unsigned short sE[16 * 520];   // e1 -> attn weights (in-place)
  __shared__ float sfin[16];
  const int bid = ((blockIdx.x & 7) << 10) | (blockIdx.x >> 3);  // XCD swizzle (8192 = 8*1024)
  const int h = bid & 15, qt = (bid >> 4) & 31, b = bid >> 9;
  const int bh = b * 16 + h;
  const int tid = threadIdx.x, w = tid >> 6, l = tid & 63;
  const int lr = l & 15, lq = l >> 4;
  const unsigned short* qp = qg + ((size_t)bh * 512 + qt * 16) * 64;
  const unsigned short* kp = kg + (size_t)bh * 512 * 64;
  const unsigned short* vp = vt + (size_t)bh * 64 * 512;

  // prefetch this wave's mask bytes (8 x 1B) — hides HBM latency under Phase A
  const unsigned char* mrb = mbits + ((size_t)(b * 512 + qt * 16)) * 64;
  const unsigned char* wrb = wbits + ((size_t)(b * 512 + qt * 16)) * 64;
  unsigned int mby[4], wby[4];
  #pragma unroll
  for (int rr = 0; rr < 4; rr++){
    mby[rr] = mrb[(w * 4 + rr) * 64 + l];
    wby[rr] = wrb[(w * 4 + rr) * 64 + l];
  }

  // ---- Phase A: QK^T over this wave's 128-col k-slice, exp -> bf16 LDS ----
  short8 qa0 = *(const short8*)(qp + lr * 64 + lq * 8);
  short8 qa1 = *(const short8*)(qp + lr * 64 + 32 + lq * 8);
  f32x4 acc[8];
  #pragma unroll
  for (int kf = 0; kf < 8; kf++){
    const unsigned short* kr = kp + (size_t)(w * 128 + kf * 16 + lr) * 64;
    short8 k0 = *(const short8*)(kr + lq * 8);
    short8 k1 = *(const short8*)(kr + 32 + lq * 8);
    f32x4 a = {};
    a = MFMA_BF16(qa0, k0, a);
    a = MFMA_BF16(qa1, k1, a);
    acc[kf] = a;
  }
  const float CEXP = 0.18033688011112042f;   // 0.125 * log2(e)
  #pragma unroll
  for (int kf = 0; kf < 8; kf++){
    float a0 = __builtin_amdgcn_exp2f(acc[kf][0] * CEXP);
    float a1 = __builtin_amdgcn_exp2f(acc[kf][1] * CEXP);
    float a2 = __builtin_amdgcn_exp2f(acc[kf][2] * CEXP);
    float a3 = __builtin_amdgcn_exp2f(acc[kf][3] * CEXP);
    unsigned int p01 = cvtpk(a0, a1), p23 = cvtpk(a2, a3);
    const int row = lq * 4;
    const int col = w * 128 + kf * 16 + lr;
    sE[(row    ) * 520 + col] = (unsigned short)(p01 & 0xFFFFu);
    sE[(row + 1) * 520 + col] = (unsigned short)(p01 >> 16);
    sE[(row + 2) * 520 + col] = (unsigned short)(p23 & 0xFFFFu);
    sE[(row + 3) * 520 + col] = (unsigned short)(p23 >> 16);
  }
  __syncthreads();

  // ---- Phase B: double masked softmax, 4 rows per wave, interleaved chains ----
  {
    uint4 ev[4];
    #pragma unroll
    for (int rr = 0; rr < 4; rr++)
      ev[rr] = *(const uint4*)(sE + (w * 4 + rr) * 520 + l * 8);

    float em[4][8]; float z1[4];
    #pragma unroll
    for (int rr = 0; rr < 4; rr++){
      float e1[8];
      unpack8(ev[rr], e1);
      const unsigned int mb = mby[rr];
      float z = 0.f;
      #pragma unroll
      for (int j = 0; j < 8; j++){
        em[rr][j] = ((mb >> j) & 1u) ? e1[j] : 0.f;
        z += em[rr][j];
      }
      z1[rr] = z;
    }
    #pragma unroll
    for (int m = 32; m; m >>= 1){
      #pragma unroll
      for (int rr = 0; rr < 4; rr++) z1[rr] += __shfl_xor(z1[rr], m, 64);
    }
    float e2[4][8]; float z2[4];
    #pragma unroll
    for (int rr = 0; rr < 4; rr++){
      const float i1L = 1.4426950408889634f / z1[rr];
      const unsigned int wv = wby[rr];
      float z = 0.f;
      #pragma unroll
      for (int j = 0; j < 8; j++){
        float t = __builtin_amdgcn_exp2f(em[rr][j] * i1L);
        e2[rr][j] = ((wv >> j) & 1u) ? t : 0.f;
        z += e2[rr][j];
      }
      z2[rr] = z;
    }
    #pragma unroll
    for (int m = 32; m; m >>= 1){
      #pragma unroll
      for (int rr = 0; rr < 4; rr++) z2[rr] += __shfl_xor(z2[rr], m, 64);
    }
    #pragma unroll
    for (int rr = 0; rr < 4; rr++){
      uint4 o;
      o.x = cvtpk(e2[rr][0], e2[rr][1]); o.y = cvtpk(e2[rr][2], e2[rr][3]);
      o.z = cvtpk(e2[rr][4], e2[rr][5]); o.w = cvtpk(e2[rr][6], e2[rr][7]);
      *(uint4*)(sE + (w * 4 + rr) * 520 + l * 8) = o;
      if (l == 0) sfin[w * 4 + rr] = 1.f / (z2[rr] + 1e-10f);
    }
  }
  __syncthreads();

  // ---- Phase C: out d-frag [16w,16w+16) over full k, direct store ----
  {
    f32x4 po = {};
    #pragma unroll
    for (int ks = 0; ks < 16; ks++){
      short8 af = *(const short8*)(sE + lr * 520 + ks * 32 + lq * 8);
      short8 vf = *(const short8*)(vp + (size_t)(w * 16 + lr) * 512 + ks * 32 + lq * 8);
      po = MFMA_BF16(af, vf, po);
    }
    #pragma unroll
    for (int rg = 0; rg < 4; rg++){
      const int row = lq * 4 + rg;
      outp[((size_t)(qt * 16 + row) * 16 + b) * 1024 + h * 64 + w * 16 + lr]
          = po[rg] * sfin[row];
    }
  }
}

// ---------------- gate + mix ----------------
__global__ __launch_bounds__(256) void gate_kernel(
    const float* __restrict__ outp, const float* __restrict__ rb,
    const float* __restrict__ wba, const float* __restrict__ wbb,
    float* __restrict__ y)
{
  const int t = blockIdx.x * 4 + (threadIdx.x >> 6);
  const int l = threadIdx.x & 63;
  const float* o = outp + (size_t)t * 1024;
  const float* r = rb + (size_t)t * 1024;
  float ov[16], rv[16];
  float acc = 0.f;
  #pragma unroll
  for (int j = 0; j < 16; j++){
    const int e = j * 64 + l;
    ov[j] = o[e]; rv[j] = r[e];
    acc += ov[j] * wba[e] + rv[j] * wbb[e];
  }
  const float dot = wred_sum(acc);
  const float g = 1.f / (1.f + __builtin_amdgcn_exp2f(-dot * 1.4426950408889634f));
  float* yo = y + (size_t)t * 1024;
  #pragma unroll
  for (int j = 0; j < 16; j++){
    const int e = j * 64 + l;
    yo[e] = g * rv[j] + (1.f - g) * ov[j];
  }
}

// ---------------- launch ----------------
extern "C" void kernel_launch(void* const* d_in, const int* in_sizes, int n_in,
                              void* d_out, int out_size, void* d_ws, size_t ws_size,
                              hipStream_t stream)
{
  (void)in_sizes; (void)n_in; (void)out_size; (void)ws_size;
  const float* x   = (const float*)d_in[0];
  const int* mask  = (const int*)d_in[1];
  const int* wmask = (const int*)d_in[2];
  const float* Wq  = (const float*)d_in[3];
  const float* Wk  = (const float*)d_in[4];
  const float* Wv  = (const float*)d_in[5];
  const float* Ws  = (const float*)d_in[6];
  const float* Wb  = (const float*)d_in[7];

  char* ws = (char*)d_ws;
  unsigned short* xbf = (unsigned short*)ws; ws += 16777216;
  unsigned short* bm  = (unsigned short*)ws; ws += 8388608;
  unsigned short* qb  = (unsigned short*)ws; ws += 16777216;
  unsigned short* kb  = (unsigned short*)ws; ws += 16777216;
  unsigned short* vT  = (unsigned short*)ws; ws += 16777216;
  float* rb  = (float*)ws; ws += 33554432;
  float* op  = (float*)ws; ws += 33554432;
  float* wba = (float*)ws; ws += 4096;
  float* wbb = (float*)ws; ws += 4096;
  // mask bit planes (4.2MB each) reuse xbf (dead after gemm) and bm
  unsigned long long* mb64 = (unsigned long long*)xbf;
  unsigned long long* wb64 = (unsigned long long*)bm;

  cvt_x_kernel<<<8192, 256, 0, stream>>>(x, xbf);
  cvt_w_kernel<<<4096, 256, 0, stream>>>(Wq, Wk, Wv, Ws, bm);
  wb_prep_kernel<<<4, 256, 0, stream>>>(Wb, wba, wbb);
  gemm_proj_kernel<<<2048, 256, 0, stream>>>(xbf, bm, qb, kb, vT, rb);
  mask_prep_kernel<<<16384, 256, 0, stream>>>(mask, wmask, mb64, wb64);
  attn_kernel<<<8192, 256, 0, stream>>>(qb, kb, vT,
      (const unsigned char*)mb64, (const unsigned char*)wb64, op);
  gate_kernel<<<2048, 256, 0, stream>>>(op, rb, wba, wbb, (float*)d_out);
}

// Round 7
// 208.827 us; speedup vs baseline: 2.8327x; 1.2599x over previous
//
#include <hip/hip_runtime.h>
#include <hip/hip_bf16.h>
#include <stdint.h>

typedef __attribute__((ext_vector_type(8))) short short8;
typedef __attribute__((ext_vector_type(4))) float f32x4;
typedef __attribute__((ext_vector_type(4))) unsigned short ushort4v;

#define MFMA_BF16(a,b,c) __builtin_amdgcn_mfma_f32_16x16x32_bf16((a),(b),(c),0,0,0)

static __device__ __forceinline__ unsigned short f2bf(float f){
  union { float fv; unsigned int u; } c; c.fv = f;
  unsigned int u = c.u;
  return (unsigned short)((u + 0x7fffu + ((u >> 16) & 1u)) >> 16);
}

static __device__ __forceinline__ unsigned int cvtpk(float a, float b){
  unsigned int r;
  asm("v_cvt_pk_bf16_f32 %0, %1, %2" : "=v"(r) : "v"(a), "v"(b));
  return r;
}

static __device__ __forceinline__ void gload_lds16(const void* g, void* l){
  __builtin_amdgcn_global_load_lds(
      (const __attribute__((address_space(1))) void*)g,
      (__attribute__((address_space(3))) void*)l, 16, 0, 0);
}

static __device__ __forceinline__ float wred_sum(float v){
  #pragma unroll
  for (int m = 32; m; m >>= 1) v += __shfl_xor(v, m, 64);
  return v;
}

static __device__ __forceinline__ void unpack8(uint4 u, float* f){
  f[0] = __uint_as_float(u.x << 16); f[1] = __uint_as_float(u.x & 0xFFFF0000u);
  f[2] = __uint_as_float(u.y << 16); f[3] = __uint_as_float(u.y & 0xFFFF0000u);
  f[4] = __uint_as_float(u.z << 16); f[5] = __uint_as_float(u.z & 0xFFFF0000u);
  f[6] = __uint_as_float(u.w << 16); f[7] = __uint_as_float(u.w & 0xFFFF0000u);
}

// ---------------- conversion kernels ----------------
__global__ __launch_bounds__(256) void cvt_x_kernel(const float* __restrict__ x,
                                                    unsigned short* __restrict__ o){
  int i = blockIdx.x * 256 + threadIdx.x;
  float4 f = ((const float4*)x)[i];
  ushort4v r;
  r[0] = f2bf(f.x); r[1] = f2bf(f.y); r[2] = f2bf(f.z); r[3] = f2bf(f.w);
  ((ushort4v*)o)[i] = r;
}

__global__ __launch_bounds__(256) void cvt_w_kernel(const float* __restrict__ Wq,
                                                    const float* __restrict__ Wk,
                                                    const float* __restrict__ Wv,
                                                    const float* __restrict__ Ws,
                                                    unsigned short* __restrict__ B){
  int i = blockIdx.x * 256 + threadIdx.x;
  int which = i >> 18;
  const float* src = (which == 0) ? Wq : (which == 1) ? Wk : (which == 2) ? Wv : Ws;
  float4 f = ((const float4*)src)[i & 262143];
  ushort4v r;
  r[0] = f2bf(f.x); r[1] = f2bf(f.y); r[2] = f2bf(f.z); r[3] = f2bf(f.w);
  ((ushort4v*)B)[i] = r;
}

__global__ void wb_prep_kernel(const float* __restrict__ Wb,
                               float* __restrict__ wba, float* __restrict__ wbb){
  int e = blockIdx.x * 256 + threadIdx.x;
  if (e < 1024){
    wba[e] = Wb[e]        + Wb[2048 + e];
    wbb[e] = Wb[1024 + e] - Wb[2048 + e];
  }
}

// masks -> bit planes via ballot
__global__ __launch_bounds__(256) void mask_prep_kernel(
    const int* __restrict__ m, const int* __restrict__ wm,
    unsigned long long* __restrict__ mb, unsigned long long* __restrict__ wb)
{
  const size_t i = (size_t)blockIdx.x * 256 + threadIdx.x;
  const int a = m[i];
  const int c = wm[i];
  unsigned long long ba = __ballot(a != 0);
  unsigned long long bc = __ballot(c != 0);
  if ((threadIdx.x & 63) == 0){
    mb[i >> 6] = ba;
    wb[i >> 6] = bc;
  }
}

// ---------------- fused projection GEMM ----------------
__global__ __launch_bounds__(256, 3) void gemm_proj_kernel(
    const unsigned short* __restrict__ X, const unsigned short* __restrict__ B,
    unsigned short* __restrict__ qb, unsigned short* __restrict__ kb,
    unsigned short* __restrict__ vT, float* __restrict__ rb)
{
  __shared__ __align__(16) unsigned short smem[128 * 136];
  unsigned short* As = smem;
  unsigned short* Bs = smem + 4096;
  const int tid = threadIdx.x;
  const int w = tid >> 6, l = tid & 63;
  const int lr = l & 15, lq = l >> 4;
  const int wr = w >> 1, wc = w & 1;
  const int bid = ((blockIdx.x & 7) << 8) | (blockIdx.x >> 3);
  const int m0 = (bid >> 5) * 128;
  const int n0 = (bid & 31) * 128;
  f32x4 acc[4][4] = {};

  for (int k0 = 0; k0 < 1024; k0 += 32){
    #pragma unroll
    for (int i = 0; i < 2; i++){
      int c = i * 256 + tid;
      gload_lds16(X + (size_t)(m0 + (c >> 2)) * 1024 + k0 + (c & 3) * 8,
                  As + (i * 256 + w * 64) * 8);
      gload_lds16(B + (size_t)(n0 + (c >> 2)) * 1024 + k0 + (c & 3) * 8,
                  Bs + (i * 256 + w * 64) * 8);
    }
    __syncthreads();
    short8 av[4], bv[4];
    #pragma unroll
    for (int mf = 0; mf < 4; mf++)
      av[mf] = *(const short8*)(As + (wr * 64 + mf * 16 + lr) * 32 + lq * 8);
    #pragma unroll
    for (int nf = 0; nf < 4; nf++)
      bv[nf] = *(const short8*)(Bs + (wc * 64 + nf * 16 + lr) * 32 + lq * 8);
    #pragma unroll
    for (int mf = 0; mf < 4; mf++)
      #pragma unroll
      for (int nf = 0; nf < 4; nf++)
        acc[mf][nf] = MFMA_BF16(av[mf], bv[nf], acc[mf][nf]);
    __syncthreads();
  }

  const int which = (n0 >> 10);
  if (which == 3){
    #pragma unroll
    for (int mf = 0; mf < 4; mf++)
      #pragma unroll
      for (int nf = 0; nf < 4; nf++){
        const int o = (n0 & 1023) + wc * 64 + nf * 16 + lr;
        #pragma unroll
        for (int rg = 0; rg < 4; rg++){
          const int rowi = m0 + wr * 64 + mf * 16 + lq * 4 + rg;
          rb[(size_t)rowi * 1024 + o] = acc[mf][nf][rg];
        }
      }
  } else if (which == 2){
    #pragma unroll
    for (int mf = 0; mf < 4; mf++)
      #pragma unroll
      for (int nf = 0; nf < 4; nf++){
        const int r0 = wr * 64 + mf * 16 + lq * 4;
        const int c  = wc * 64 + nf * 16 + lr;
        uint2 pk;
        pk.x = cvtpk(acc[mf][nf][0], acc[mf][nf][1]);
        pk.y = cvtpk(acc[mf][nf][2], acc[mf][nf][3]);
        *(uint2*)(smem + c * 132 + r0) = pk;
      }
    __syncthreads();
    const int s0 = m0 >> 4;
    #pragma unroll
    for (int p = 0; p < 8; p++){
      const int cid = p * 256 + tid;
      const int c = cid >> 4, bb = cid & 15;
      short8 st;
      #pragma unroll
      for (int j = 0; j < 8; j++) st[j] = (short)smem[c * 132 + j * 16 + bb];
      const int o = (n0 & 1023) + c;
      const int bh = bb * 16 + (o >> 6), d = o & 63;
      *(short8*)(vT + ((size_t)bh * 64 + d) * 512 + s0) = st;
    }
  } else {
    #pragma unroll
    for (int mf = 0; mf < 4; mf++)
      #pragma unroll
      for (int nf = 0; nf < 4; nf++)
        #pragma unroll
        for (int rg = 0; rg < 4; rg++)
          smem[(wr * 64 + mf * 16 + lq * 4 + rg) * 136 + wc * 64 + nf * 16 + lr]
              = f2bf(acc[mf][nf][rg]);
    __syncthreads();
    unsigned short* dst = (which == 0) ? qb : kb;
    #pragma unroll
    for (int p = 0; p < 8; p++){
      const int cid = p * 256 + tid;
      const int lrow = cid >> 4, cg = cid & 15;
      short8 vv = *(const short8*)(smem + lrow * 136 + cg * 8);
      const int rowi = m0 + lrow;
      const int s = rowi >> 4, bb = rowi & 15;
      const int o = (n0 & 1023) + cg * 8;
      const int bh = bb * 16 + (o >> 6), d = o & 63;
      *(short8*)(dst + ((size_t)bh * 512 + s) * 64 + d) = vv;
    }
  }
}

// ---------------- fused attention ----------------
// 32 q-rows/block, 4 waves, 4096 blocks. Two independent MFMA chains per wave
// in Phase A (2 q-subtiles sharing K frags) and Phase C (2 po chains sharing V
// frags) for ILP; K/V traffic per q-row halved vs 16-row blocks.
__global__ __launch_bounds__(256, 4) void attn_kernel(
    const unsigned short* __restrict__ qg, const unsigned short* __restrict__ kg,
    const unsigned short* __restrict__ vt,
    const unsigned char* __restrict__ mbits, const unsigned char* __restrict__ wbits,
    float* __restrict__ outp)
{
  __shared__ __align__(16) unsigned short sE[32 * 520];
  __shared__ float sfin[32];
  const int bid = ((blockIdx.x & 7) << 9) | (blockIdx.x >> 3);  // XCD swizzle (4096 = 8*512)
  const int qt = bid & 15, h = (bid >> 4) & 15, b = bid >> 8;   // qt-fastest: K/V L2 reuse
  const int tid = threadIdx.x, w = tid >> 6, l = tid & 63;
  const int lr = l & 15, lq = l >> 4;
  const int bh = b * 16 + h;
  const unsigned short* qp = qg + ((size_t)bh * 512 + qt * 32) * 64;
  const unsigned short* kp = kg + (size_t)bh * 512 * 64;
  const unsigned short* vp = vt + (size_t)bh * 64 * 512;

  // prefetch mask bytes for this wave's 8 rows (2 groups of 4)
  const unsigned char* mrb = mbits + ((size_t)(b * 512 + qt * 32)) * 64;
  const unsigned char* wrb = wbits + ((size_t)(b * 512 + qt * 32)) * 64;
  unsigned int mby[2][4], wby[2][4];
  #pragma unroll
  for (int g = 0; g < 2; g++)
    #pragma unroll
    for (int rr = 0; rr < 4; rr++){
      mby[g][rr] = mrb[(g * 16 + w * 4 + rr) * 64 + l];
      wby[g][rr] = wrb[(g * 16 + w * 4 + rr) * 64 + l];
    }

  // ---- Phase A: QK^T on 128-col k-slice for 2 q-subtiles (indep chains) ----
  short8 qa[2][2];
  #pragma unroll
  for (int t = 0; t < 2; t++){
    qa[t][0] = *(const short8*)(qp + (t * 16 + lr) * 64 + lq * 8);
    qa[t][1] = *(const short8*)(qp + (t * 16 + lr) * 64 + 32 + lq * 8);
  }
  const float CEXP = 0.18033688011112042f;   // 0.125 * log2(e)
  #pragma unroll
  for (int kf = 0; kf < 8; kf++){
    const unsigned short* kr = kp + (size_t)(w * 128 + kf * 16 + lr) * 64;
    short8 k0 = *(const short8*)(kr + lq * 8);
    short8 k1 = *(const short8*)(kr + 32 + lq * 8);
    f32x4 a0 = {}, a1 = {};
    a0 = MFMA_BF16(qa[0][0], k0, a0);
    a1 = MFMA_BF16(qa[1][0], k0, a1);
    a0 = MFMA_BF16(qa[0][1], k1, a0);
    a1 = MFMA_BF16(qa[1][1], k1, a1);
    const int col = w * 128 + kf * 16 + lr;
    #pragma unroll
    for (int t = 0; t < 2; t++){
      f32x4 a = t ? a1 : a0;
      float e0 = __builtin_amdgcn_exp2f(a[0] * CEXP);
      float e1 = __builtin_amdgcn_exp2f(a[1] * CEXP);
      float e2 = __builtin_amdgcn_exp2f(a[2] * CEXP);
      float e3 = __builtin_amdgcn_exp2f(a[3] * CEXP);
      unsigned int p01 = cvtpk(e0, e1), p23 = cvtpk(e2, e3);
      const int row = t * 16 + lq * 4;
      sE[(row    ) * 520 + col] = (unsigned short)(p01 & 0xFFFFu);
      sE[(row + 1) * 520 + col] = (unsigned short)(p01 >> 16);
      sE[(row + 2) * 520 + col] = (unsigned short)(p23 & 0xFFFFu);
      sE[(row + 3) * 520 + col] = (unsigned short)(p23 >> 16);
    }
  }
  __syncthreads();

  // ---- Phase B: double masked softmax, 2 groups x 4 interleaved rows ----
  #pragma unroll
  for (int g = 0; g < 2; g++){
    const int row0 = g * 16 + w * 4;
    uint4 ev[4];
    #pragma unroll
    for (int rr = 0; rr < 4; rr++)
      ev[rr] = *(const uint4*)(sE + (row0 + rr) * 520 + l * 8);

    float em[4][8]; float z1[4];
    #pragma unroll
    for (int rr = 0; rr < 4; rr++){
      float e1[8];
      unpack8(ev[rr], e1);
      const unsigned int mb = mby[g][rr];
      float z = 0.f;
      #pragma unroll
      for (int j = 0; j < 8; j++){
        em[rr][j] = ((mb >> j) & 1u) ? e1[j] : 0.f;
        z += em[rr][j];
      }
      z1[rr] = z;
    }
    #pragma unroll
    for (int m = 32; m; m >>= 1){
      #pragma unroll
      for (int rr = 0; rr < 4; rr++) z1[rr] += __shfl_xor(z1[rr], m, 64);
    }
    float e2[4][8]; float z2[4];
    #pragma unroll
    for (int rr = 0; rr < 4; rr++){
      const float i1L = 1.4426950408889634f / z1[rr];
      const unsigned int wv = wby[g][rr];
      float z = 0.f;
      #pragma unroll
      for (int j = 0; j < 8; j++){
        float t = __builtin_amdgcn_exp2f(em[rr][j] * i1L);
        e2[rr][j] = ((wv >> j) & 1u) ? t : 0.f;
        z += e2[rr][j];
      }
      z2[rr] = z;
    }
    #pragma unroll
    for (int m = 32; m; m >>= 1){
      #pragma unroll
      for (int rr = 0; rr < 4; rr++) z2[rr] += __shfl_xor(z2[rr], m, 64);
    }
    #pragma unroll
    for (int rr = 0; rr < 4; rr++){
      uint4 o;
      o.x = cvtpk(e2[rr][0], e2[rr][1]); o.y = cvtpk(e2[rr][2], e2[rr][3]);
      o.z = cvtpk(e2[rr][4], e2[rr][5]); o.w = cvtpk(e2[rr][6], e2[rr][7]);
      *(uint4*)(sE + (row0 + rr) * 520 + l * 8) = o;
      if (l == 0) sfin[row0 + rr] = 1.f / (z2[rr] + 1e-10f);
    }
  }
  __syncthreads();

  // ---- Phase C: 2 po chains sharing each V frag; d-frag [16w,16w+16) ----
  {
    f32x4 po0 = {}, po1 = {};
    #pragma unroll
    for (int ks = 0; ks < 16; ks++){
      short8 vf = *(const short8*)(vp + (size_t)(w * 16 + lr) * 512 + ks * 32 + lq * 8);
      short8 af0 = *(const short8*)(sE + (     lr) * 520 + ks * 32 + lq * 8);
      short8 af1 = *(const short8*)(sE + (16 + lr) * 520 + ks * 32 + lq * 8);
      po0 = MFMA_BF16(af0, vf, po0);
      po1 = MFMA_BF16(af1, vf, po1);
    }
    #pragma unroll
    for (int rg = 0; rg < 4; rg++){
      const int r0 = lq * 4 + rg;
      outp[((size_t)(qt * 32 + r0) * 16 + b) * 1024 + h * 64 + w * 16 + lr]
          = po0[rg] * sfin[r0];
      outp[((size_t)(qt * 32 + 16 + r0) * 16 + b) * 1024 + h * 64 + w * 16 + lr]
          = po1[rg] * sfin[16 + r0];
    }
  }
}

// ---------------- gate + mix ----------------
__global__ __launch_bounds__(256) void gate_kernel(
    const float* __restrict__ outp, const float* __restrict__ rb,
    const float* __restrict__ wba, const float* __restrict__ wbb,
    float* __restrict__ y)
{
  const int t = blockIdx.x * 4 + (threadIdx.x >> 6);
  const int l = threadIdx.x & 63;
  const float* o = outp + (size_t)t * 1024;
  const float* r = rb + (size_t)t * 1024;
  float ov[16], rv[16];
  float acc = 0.f;
  #pragma unroll
  for (int j = 0; j < 16; j++){
    const int e = j * 64 + l;
    ov[j] = o[e]; rv[j] = r[e];
    acc += ov[j] * wba[e] + rv[j] * wbb[e];
  }
  const float dot = wred_sum(acc);
  const float g = 1.f / (1.f + __builtin_amdgcn_exp2f(-dot * 1.4426950408889634f));
  float* yo = y + (size_t)t * 1024;
  #pragma unroll
  for (int j = 0; j < 16; j++){
    const int e = j * 64 + l;
    yo[e] = g * rv[j] + (1.f - g) * ov[j];
  }
}

// ---------------- launch ----------------
extern "C" void kernel_launch(void* const* d_in, const int* in_sizes, int n_in,
                              void* d_out, int out_size, void* d_ws, size_t ws_size,
                              hipStream_t stream)
{
  (void)in_sizes; (void)n_in; (void)out_size; (void)ws_size;
  const float* x   = (const float*)d_in[0];
  const int* mask  = (const int*)d_in[1];
  const int* wmask = (const int*)d_in[2];
  const float* Wq  = (const float*)d_in[3];
  const float* Wk  = (const float*)d_in[4];
  const float* Wv  = (const float*)d_in[5];
  const float* Ws  = (const float*)d_in[6];
  const float* Wb  = (const float*)d_in[7];

  char* ws = (char*)d_ws;
  unsigned short* xbf = (unsigned short*)ws; ws += 16777216;
  unsigned short* bm  = (unsigned short*)ws; ws += 8388608;
  unsigned short* qb  = (unsigned short*)ws; ws += 16777216;
  unsigned short* kb  = (unsigned short*)ws; ws += 16777216;
  unsigned short* vT  = (unsigned short*)ws; ws += 16777216;
  float* rb  = (float*)ws; ws += 33554432;
  float* op  = (float*)ws; ws += 33554432;
  float* wba = (float*)ws; ws += 4096;
  float* wbb = (float*)ws; ws += 4096;
  unsigned long long* mb64 = (unsigned long long*)xbf;
  unsigned long long* wb64 = (unsigned long long*)bm;

  cvt_x_kernel<<<8192, 256, 0, stream>>>(x, xbf);
  cvt_w_kernel<<<4096, 256, 0, stream>>>(Wq, Wk, Wv, Ws, bm);
  wb_prep_kernel<<<4, 256, 0, stream>>>(Wb, wba, wbb);
  gemm_proj_kernel<<<2048, 256, 0, stream>>>(xbf, bm, qb, kb, vT, rb);
  mask_prep_kernel<<<16384, 256, 0, stream>>>(mask, wmask, mb64, wb64);
  attn_kernel<<<4096, 256, 0, stream>>>(qb, kb, vT,
      (const unsigned char*)mb64, (const unsigned char*)wb64, op);
  gate_kernel<<<2048, 256, 0, stream>>>(op, rb, wba, wbb, (float*)d_out);
}

// Round 8
// 198.200 us; speedup vs baseline: 2.9846x; 1.0536x over previous
//
#include <hip/hip_runtime.h>
#include <hip/hip_bf16.h>
#include <stdint.h>

typedef __attribute__((ext_vector_type(8))) short short8;
typedef __attribute__((ext_vector_type(4))) float f32x4;
typedef __attribute__((ext_vector_type(4))) unsigned short ushort4v;

#define MFMA_BF16(a,b,c) __builtin_amdgcn_mfma_f32_16x16x32_bf16((a),(b),(c),0,0,0)

static __device__ __forceinline__ unsigned short f2bf(float f){
  union { float fv; unsigned int u; } c; c.fv = f;
  unsigned int u = c.u;
  return (unsigned short)((u + 0x7fffu + ((u >> 16) & 1u)) >> 16);
}

static __device__ __forceinline__ unsigned int cvtpk(float a, float b){
  unsigned int r;
  asm("v_cvt_pk_bf16_f32 %0, %1, %2" : "=v"(r) : "v"(a), "v"(b));
  return r;
}

static __device__ __forceinline__ void gload_lds16(const void* g, void* l){
  __builtin_amdgcn_global_load_lds(
      (const __attribute__((address_space(1))) void*)g,
      (__attribute__((address_space(3))) void*)l, 16, 0, 0);
}

static __device__ __forceinline__ float wred_sum(float v){
  #pragma unroll
  for (int m = 32; m; m >>= 1) v += __shfl_xor(v, m, 64);
  return v;
}

static __device__ __forceinline__ void unpack8(uint4 u, float* f){
  f[0] = __uint_as_float(u.x << 16); f[1] = __uint_as_float(u.x & 0xFFFF0000u);
  f[2] = __uint_as_float(u.y << 16); f[3] = __uint_as_float(u.y & 0xFFFF0000u);
  f[4] = __uint_as_float(u.z << 16); f[5] = __uint_as_float(u.z & 0xFFFF0000u);
  f[6] = __uint_as_float(u.w << 16); f[7] = __uint_as_float(u.w & 0xFFFF0000u);
}

// ---------------- conversion kernels ----------------
__global__ __launch_bounds__(256) void cvt_x_kernel(const float* __restrict__ x,
                                                    unsigned short* __restrict__ o){
  int i = blockIdx.x * 256 + threadIdx.x;
  float4 f = ((const float4*)x)[i];
  ushort4v r;
  r[0] = f2bf(f.x); r[1] = f2bf(f.y); r[2] = f2bf(f.z); r[3] = f2bf(f.w);
  ((ushort4v*)o)[i] = r;
}

__global__ __launch_bounds__(256) void cvt_w_kernel(const float* __restrict__ Wq,
                                                    const float* __restrict__ Wk,
                                                    const float* __restrict__ Wv,
                                                    const float* __restrict__ Ws,
                                                    unsigned short* __restrict__ B){
  int i = blockIdx.x * 256 + threadIdx.x;
  int which = i >> 18;
  const float* src = (which == 0) ? Wq : (which == 1) ? Wk : (which == 2) ? Wv : Ws;
  float4 f = ((const float4*)src)[i & 262143];
  ushort4v r;
  r[0] = f2bf(f.x); r[1] = f2bf(f.y); r[2] = f2bf(f.z); r[3] = f2bf(f.w);
  ((ushort4v*)B)[i] = r;
}

__global__ void wb_prep_kernel(const float* __restrict__ Wb,
                               float* __restrict__ wba, float* __restrict__ wbb){
  int e = blockIdx.x * 256 + threadIdx.x;
  if (e < 1024){
    wba[e] = Wb[e]        + Wb[2048 + e];
    wbb[e] = Wb[1024 + e] - Wb[2048 + e];
  }
}

// masks -> bit planes via ballot
__global__ __launch_bounds__(256) void mask_prep_kernel(
    const int* __restrict__ m, const int* __restrict__ wm,
    unsigned long long* __restrict__ mb, unsigned long long* __restrict__ wb)
{
  const size_t i = (size_t)blockIdx.x * 256 + threadIdx.x;
  const int a = m[i];
  const int c = wm[i];
  unsigned long long ba = __ballot(a != 0);
  unsigned long long bc = __ballot(c != 0);
  if ((threadIdx.x & 63) == 0){
    mb[i >> 6] = ba;
    wb[i >> 6] = bc;
  }
}

// ---------------- fused projection GEMM ----------------
// 256(M)x128(N) tile, 8 waves (4m x 2n), BK=32. C(8192x4096) = Xbf @ Bmat^T.
// Epilogue stages C in LDS (two passes) for coalesced 16B stores.
__global__ __launch_bounds__(512, 4) void gemm_proj_kernel(
    const unsigned short* __restrict__ X, const unsigned short* __restrict__ B,
    unsigned short* __restrict__ qb, unsigned short* __restrict__ kb,
    unsigned short* __restrict__ vT, float* __restrict__ rb)
{
  __shared__ __align__(16) unsigned short smem[17408];   // 34.8 KB
  unsigned short* As = smem;            // [256][32]
  unsigned short* Bs = smem + 8192;     // [128][32]
  const int tid = threadIdx.x;
  const int w = tid >> 6, l = tid & 63;
  const int lr = l & 15, lq = l >> 4;
  const int wr = w >> 1, wc = w & 1;    // wave out: rows [wr*64,+64), cols [wc*64,+64)
  const int bid = ((blockIdx.x & 7) << 7) | (blockIdx.x >> 3);   // XCD swizzle (1024 = 8*128)
  const int nt = bid >> 5, mt = bid & 31;                        // nt-outer: B slice L2-fits
  const int m0 = mt * 256, n0 = nt * 128;
  f32x4 acc[4][4] = {};

  for (int k0 = 0; k0 < 1024; k0 += 32){
    // stage 24KB: A 256x32 (2 chunks/thread), B 128x32 (1 chunk/thread)
    gload_lds16(X + (size_t)(m0 + (tid >> 2)) * 1024 + k0 + (tid & 3) * 8,
                As + (w * 64) * 8);
    gload_lds16(X + (size_t)(m0 + 128 + (tid >> 2)) * 1024 + k0 + (tid & 3) * 8,
                As + (512 + w * 64) * 8);
    gload_lds16(B + (size_t)(n0 + (tid >> 2)) * 1024 + k0 + (tid & 3) * 8,
                Bs + (w * 64) * 8);
    __syncthreads();
    short8 av[4], bv[4];
    #pragma unroll
    for (int mf = 0; mf < 4; mf++)
      av[mf] = *(const short8*)(As + (wr * 64 + mf * 16 + lr) * 32 + lq * 8);
    #pragma unroll
    for (int nf = 0; nf < 4; nf++)
      bv[nf] = *(const short8*)(Bs + (wc * 64 + nf * 16 + lr) * 32 + lq * 8);
    #pragma unroll
    for (int mf = 0; mf < 4; mf++)
      #pragma unroll
      for (int nf = 0; nf < 4; nf++)
        acc[mf][nf] = MFMA_BF16(av[mf], bv[nf], acc[mf][nf]);
    __syncthreads();
  }

  const int which = nt >> 3;
  const int o0 = n0 & 1023;
  if (which == 3){
    // r: fp32 direct stores (16-lane 64B runs)
    #pragma unroll
    for (int mf = 0; mf < 4; mf++)
      #pragma unroll
      for (int nf = 0; nf < 4; nf++){
        const int o = o0 + wc * 64 + nf * 16 + lr;
        #pragma unroll
        for (int rg = 0; rg < 4; rg++){
          const int rowi = m0 + wr * 64 + mf * 16 + lq * 4 + rg;
          rb[(size_t)rowi * 1024 + o] = acc[mf][nf][rg];
        }
      }
  } else if (which == 2){
    // v transposed: two col-half passes, LDS [64 cols][264 rows-pad]
    #pragma unroll
    for (int ch = 0; ch < 2; ch++){
      __syncthreads();
      if (wc == ch){
        #pragma unroll
        for (int mf = 0; mf < 4; mf++)
          #pragma unroll
          for (int nf = 0; nf < 4; nf++){
            const int cl = nf * 16 + lr;
            const int r0 = wr * 64 + mf * 16 + lq * 4;
            uint2 pk;
            pk.x = cvtpk(acc[mf][nf][0], acc[mf][nf][1]);
            pk.y = cvtpk(acc[mf][nf][2], acc[mf][nf][3]);
            *(uint2*)(smem + cl * 264 + r0) = pk;
          }
      }
      __syncthreads();
      #pragma unroll
      for (int p = 0; p < 4; p++){
        const int cid = p * 512 + tid;       // 2048 chunks: 64 cl x 16 bb x 2 sh
        const int cl = cid >> 5, bb = (cid >> 1) & 15, sh = cid & 1;
        short8 st;
        #pragma unroll
        for (int jj = 0; jj < 8; jj++)
          st[jj] = (short)smem[cl * 264 + (sh * 8 + jj) * 16 + bb];
        const int o = o0 + ch * 64 + cl;
        const int bh = bb * 16 + (o >> 6), d = o & 63;
        *(short8*)(vT + ((size_t)bh * 64 + d) * 512 + (m0 >> 4) + sh * 8) = st;
      }
    }
  } else {
    // q/k: two row-half passes, LDS [128 rows][136]
    unsigned short* dst = which ? kb : qb;
    #pragma unroll
    for (int h2 = 0; h2 < 2; h2++){
      __syncthreads();
      if ((wr >> 1) == h2){
        #pragma unroll
        for (int mf = 0; mf < 4; mf++)
          #pragma unroll
          for (int nf = 0; nf < 4; nf++)
            #pragma unroll
            for (int rg = 0; rg < 4; rg++)
              smem[((wr & 1) * 64 + mf * 16 + lq * 4 + rg) * 136 + wc * 64 + nf * 16 + lr]
                  = f2bf(acc[mf][nf][rg]);
      }
      __syncthreads();
      #pragma unroll
      for (int p = 0; p < 4; p++){
        const int cid = p * 512 + tid;       // 2048 chunks: 128 rows x 16 cg
        const int lrow = cid >> 4, cg = cid & 15;
        short8 vv = *(const short8*)(smem + lrow * 136 + cg * 8);
        const int rowi = m0 + h2 * 128 + lrow;
        const int s = rowi >> 4, bb2 = rowi & 15;
        const int o = o0 + cg * 8;
        const int bh = bb2 * 16 + (o >> 6), d = o & 63;
        *(short8*)(dst + ((size_t)bh * 512 + s) * 64 + d) = vv;
      }
    }
  }
}

// ---------------- fused attention ----------------
// 32 q-rows/block, 4 waves, 4096 blocks; bf16 out.
__global__ __launch_bounds__(256, 4) void attn_kernel(
    const unsigned short* __restrict__ qg, const unsigned short* __restrict__ kg,
    const unsigned short* __restrict__ vt,
    const unsigned char* __restrict__ mbits, const unsigned char* __restrict__ wbits,
    unsigned short* __restrict__ outp)
{
  __shared__ __align__(16) unsigned short sE[32 * 520];
  __shared__ float sfin[32];
  const int bid = ((blockIdx.x & 7) << 9) | (blockIdx.x >> 3);  // XCD swizzle (4096 = 8*512)
  const int qt = bid & 15, h = (bid >> 4) & 15, b = bid >> 8;   // qt-fastest: K/V L2 reuse
  const int tid = threadIdx.x, w = tid >> 6, l = tid & 63;
  const int lr = l & 15, lq = l >> 4;
  const int bh = b * 16 + h;
  const unsigned short* qp = qg + ((size_t)bh * 512 + qt * 32) * 64;
  const unsigned short* kp = kg + (size_t)bh * 512 * 64;
  const unsigned short* vp = vt + (size_t)bh * 64 * 512;

  const unsigned char* mrb = mbits + ((size_t)(b * 512 + qt * 32)) * 64;
  const unsigned char* wrb = wbits + ((size_t)(b * 512 + qt * 32)) * 64;
  unsigned int mby[2][4], wby[2][4];
  #pragma unroll
  for (int g = 0; g < 2; g++)
    #pragma unroll
    for (int rr = 0; rr < 4; rr++){
      mby[g][rr] = mrb[(g * 16 + w * 4 + rr) * 64 + l];
      wby[g][rr] = wrb[(g * 16 + w * 4 + rr) * 64 + l];
    }

  // ---- Phase A: QK^T on 128-col k-slice for 2 q-subtiles (indep chains) ----
  short8 qa[2][2];
  #pragma unroll
  for (int t = 0; t < 2; t++){
    qa[t][0] = *(const short8*)(qp + (t * 16 + lr) * 64 + lq * 8);
    qa[t][1] = *(const short8*)(qp + (t * 16 + lr) * 64 + 32 + lq * 8);
  }
  const float CEXP = 0.18033688011112042f;   // 0.125 * log2(e)
  #pragma unroll
  for (int kf = 0; kf < 8; kf++){
    const unsigned short* kr = kp + (size_t)(w * 128 + kf * 16 + lr) * 64;
    short8 k0 = *(const short8*)(kr + lq * 8);
    short8 k1 = *(const short8*)(kr + 32 + lq * 8);
    f32x4 a0 = {}, a1 = {};
    a0 = MFMA_BF16(qa[0][0], k0, a0);
    a1 = MFMA_BF16(qa[1][0], k0, a1);
    a0 = MFMA_BF16(qa[0][1], k1, a0);
    a1 = MFMA_BF16(qa[1][1], k1, a1);
    const int col = w * 128 + kf * 16 + lr;
    #pragma unroll
    for (int t = 0; t < 2; t++){
      f32x4 a = t ? a1 : a0;
      float e0 = __builtin_amdgcn_exp2f(a[0] * CEXP);
      float e1 = __builtin_amdgcn_exp2f(a[1] * CEXP);
      float e2 = __builtin_amdgcn_exp2f(a[2] * CEXP);
      float e3 = __builtin_amdgcn_exp2f(a[3] * CEXP);
      unsigned int p01 = cvtpk(e0, e1), p23 = cvtpk(e2, e3);
      const int row = t * 16 + lq * 4;
      sE[(row    ) * 520 + col] = (unsigned short)(p01 & 0xFFFFu);
      sE[(row + 1) * 520 + col] = (unsigned short)(p01 >> 16);
      sE[(row + 2) * 520 + col] = (unsigned short)(p23 & 0xFFFFu);
      sE[(row + 3) * 520 + col] = (unsigned short)(p23 >> 16);
    }
  }
  __syncthreads();

  // ---- Phase B: double masked softmax, 2 groups x 4 interleaved rows ----
  #pragma unroll
  for (int g = 0; g < 2; g++){
    const int row0 = g * 16 + w * 4;
    uint4 ev[4];
    #pragma unroll
    for (int rr = 0; rr < 4; rr++)
      ev[rr] = *(const uint4*)(sE + (row0 + rr) * 520 + l * 8);

    float em[4][8]; float z1[4];
    #pragma unroll
    for (int rr = 0; rr < 4; rr++){
      float e1[8];
      unpack8(ev[rr], e1);
      const unsigned int mb = mby[g][rr];
      float z = 0.f;
      #pragma unroll
      for (int j = 0; j < 8; j++){
        em[rr][j] = ((mb >> j) & 1u) ? e1[j] : 0.f;
        z += em[rr][j];
      }
      z1[rr] = z;
    }
    #pragma unroll
    for (int m = 32; m; m >>= 1){
      #pragma unroll
      for (int rr = 0; rr < 4; rr++) z1[rr] += __shfl_xor(z1[rr], m, 64);
    }
    float e2[4][8]; float z2[4];
    #pragma unroll
    for (int rr = 0; rr < 4; rr++){
      const float i1L = 1.4426950408889634f / z1[rr];
      const unsigned int wv = wby[g][rr];
      float z = 0.f;
      #pragma unroll
      for (int j = 0; j < 8; j++){
        float t = __builtin_amdgcn_exp2f(em[rr][j] * i1L);
        e2[rr][j] = ((wv >> j) & 1u) ? t : 0.f;
        z += e2[rr][j];
      }
      z2[rr] = z;
    }
    #pragma unroll
    for (int m = 32; m; m >>= 1){
      #pragma unroll
      for (int rr = 0; rr < 4; rr++) z2[rr] += __shfl_xor(z2[rr], m, 64);
    }
    #pragma unroll
    for (int rr = 0; rr < 4; rr++){
      uint4 o;
      o.x = cvtpk(e2[rr][0], e2[rr][1]); o.y = cvtpk(e2[rr][2], e2[rr][3]);
      o.z = cvtpk(e2[rr][4], e2[rr][5]); o.w = cvtpk(e2[rr][6], e2[rr][7]);
      *(uint4*)(sE + (row0 + rr) * 520 + l * 8) = o;
      if (l == 0) sfin[row0 + rr] = 1.f / (z2[rr] + 1e-10f);
    }
  }
  __syncthreads();

  // ---- Phase C: 2 po chains sharing each V frag; d-frag [16w,16w+16) ----
  {
    f32x4 po0 = {}, po1 = {};
    #pragma unroll
    for (int ks = 0; ks < 16; ks++){
      short8 vf = *(const short8*)(vp + (size_t)(w * 16 + lr) * 512 + ks * 32 + lq * 8);
      short8 af0 = *(const short8*)(sE + (     lr) * 520 + ks * 32 + lq * 8);
      short8 af1 = *(const short8*)(sE + (16 + lr) * 520 + ks * 32 + lq * 8);
      po0 = MFMA_BF16(af0, vf, po0);
      po1 = MFMA_BF16(af1, vf, po1);
    }
    #pragma unroll
    for (int rg = 0; rg < 4; rg++){
      const int r0 = lq * 4 + rg;
      outp[((size_t)(qt * 32 + r0) * 16 + b) * 1024 + h * 64 + w * 16 + lr]
          = f2bf(po0[rg] * sfin[r0]);
      outp[((size_t)(qt * 32 + 16 + r0) * 16 + b) * 1024 + h * 64 + w * 16 + lr]
          = f2bf(po1[rg] * sfin[16 + r0]);
    }
  }
}

// ---------------- gate + mix ----------------
__global__ __launch_bounds__(256) void gate_kernel(
    const unsigned short* __restrict__ outp, const float* __restrict__ rb,
    const float* __restrict__ wba, const float* __restrict__ wbb,
    float* __restrict__ y)
{
  const int t = blockIdx.x * 4 + (threadIdx.x >> 6);
  const int l = threadIdx.x & 63;
  const unsigned short* o = outp + (size_t)t * 1024;
  const float* r = rb + (size_t)t * 1024;
  float ov[16], rv[16];
  float acc = 0.f;
  #pragma unroll
  for (int j = 0; j < 16; j++){
    const int e = j * 64 + l;
    ov[j] = __uint_as_float((unsigned int)o[e] << 16);
    rv[j] = r[e];
    acc += ov[j] * wba[e] + rv[j] * wbb[e];
  }
  const float dot = wred_sum(acc);
  const float g = 1.f / (1.f + __builtin_amdgcn_exp2f(-dot * 1.4426950408889634f));
  float* yo = y + (size_t)t * 1024;
  #pragma unroll
  for (int j = 0; j < 16; j++){
    const int e = j * 64 + l;
    yo[e] = g * rv[j] + (1.f - g) * ov[j];
  }
}

// ---------------- launch ----------------
extern "C" void kernel_launch(void* const* d_in, const int* in_sizes, int n_in,
                              void* d_out, int out_size, void* d_ws, size_t ws_size,
                              hipStream_t stream)
{
  (void)in_sizes; (void)n_in; (void)out_size; (void)ws_size;
  const float* x   = (const float*)d_in[0];
  const int* mask  = (const int*)d_in[1];
  const int* wmask = (const int*)d_in[2];
  const float* Wq  = (const float*)d_in[3];
  const float* Wk  = (const float*)d_in[4];
  const float* Wv  = (const float*)d_in[5];
  const float* Ws  = (const float*)d_in[6];
  const float* Wb  = (const float*)d_in[7];

  char* ws = (char*)d_ws;
  unsigned short* xbf = (unsigned short*)ws; ws += 16777216;
  unsigned short* bm  = (unsigned short*)ws; ws += 8388608;
  unsigned short* qb  = (unsigned short*)ws; ws += 16777216;
  unsigned short* kb  = (unsigned short*)ws; ws += 16777216;
  unsigned short* vT  = (unsigned short*)ws; ws += 16777216;
  float* rb  = (float*)ws; ws += 33554432;
  unsigned short* op = (unsigned short*)ws; ws += 33554432;
  float* wba = (float*)ws; ws += 4096;
  float* wbb = (float*)ws; ws += 4096;
  unsigned long long* mb64 = (unsigned long long*)xbf;
  unsigned long long* wb64 = (unsigned long long*)bm;

  cvt_x_kernel<<<8192, 256, 0, stream>>>(x, xbf);
  cvt_w_kernel<<<4096, 256, 0, stream>>>(Wq, Wk, Wv, Ws, bm);
  wb_prep_kernel<<<4, 256, 0, stream>>>(Wb, wba, wbb);
  gemm_proj_kernel<<<1024, 512, 0, stream>>>(xbf, bm, qb, kb, vT, rb);
  mask_prep_kernel<<<16384, 256, 0, stream>>>(mask, wmask, mb64, wb64);
  attn_kernel<<<4096, 256, 0, stream>>>(qb, kb, vT,
      (const unsigned char*)mb64, (const unsigned char*)wb64, op);
  gate_kernel<<<2048, 256, 0, stream>>>(op, rb, wba, wbb, (float*)d_out);
}